// Round 1
// 925.367 us; speedup vs baseline: 1.1859x; 1.1859x over previous
//
#include <hip/hip_runtime.h>
#include <hip/hip_bf16.h>
#include <hip/hip_fp16.h>

#define N_NODES 16384
#define E_EDGES 262144

#define SCALE_S 0.09128709291752768f   // 1/sqrt(120)
#define SCALE_E 0.09449111825230679f   // 1/sqrt(112)

// ---- workspace layout (bytes) ----
#define OFF_ACC   256                       // accS N*120 f32 | accE N*240 f32
#define ACC_BYTES ((size_t)N_NODES * 360 * 4)
#define OFF_TAB   (OFF_ACC + ACC_BYTES)     // 23,593,216 ; tab N*952 bf16
#define OFF_NS    (OFF_TAB + (size_t)N_NODES * 952 * 2)   // 54,788,352 ; NS N*128 bf16
#define OFF_W1T   (OFF_NS + (size_t)N_NODES * 128 * 2)    // 58,982,656 ; 256*160 bf16
#define OFF_W2T   (OFF_W1T + 256 * 160 * 2)               // +81,920    ; 128*256 bf16
#define OFF_WNT   (OFF_W2T + 128 * 256 * 2)               // +65,536    ; 768*128 bf16
#define OFF_B1    (OFF_WNT + 768 * 128 * 2)               // +196,608   ; 256 f32
#define OFF_B2    (OFF_B1 + 1024)                          // 128 f32
#define OFF_WIJ   (OFF_B2 + 512)                           // E*128 bf16 = 67,108,864

typedef __attribute__((ext_vector_type(8))) short short8;
typedef __attribute__((ext_vector_type(4))) float f32x4;

// padded LDS strides (shorts) to spread banks
#define SF_STRIDE 168   // rows of F  (160 used)
#define SB_STRIDE 40    // rows of B  (32 used)
#define TR_STRIDE 40    // per-wave H transpose buffer rows (32 used)

// mlp LDS layout:
//   sF   : 64*SF_STRIDE*2        = 21504 B
//   region1 (union):
//     sD : 64*240*2 (fp16 sq-diffs) = 30720 B   [feature stage only]
//     sB : 256*SB_STRIDE*2          = 20480 B   [GEMM stages]
//     sTr: 4*16*TR_STRIDE*2         =  5120 B   [GEMM2, at region1+20480]
//   sFc  : 64*4                  =   256 B
//   sIdx : 2*64*4                =   512 B
#define REGION1_BYTES (64 * 240 * 2)
#define SMEM_MLP (64 * SF_STRIDE * 2 + REGION1_BYTES + 64 * 4 + 2 * 64 * 4)

static __device__ __forceinline__ float b2f(short s) {
    return __uint_as_float(((unsigned int)(unsigned short)s) << 16);
}
static __device__ __forceinline__ short f2b(float v) {
    __hip_bfloat16 h = __float2bfloat16(v);
    return *reinterpret_cast<short*>(&h);
}
static __device__ __forceinline__ short f2h(float v) {
    __half h = __float2half(v);
    return *reinterpret_cast<short*>(&h);
}
static __device__ __forceinline__ float h2f(short s) {
    __half h = *reinterpret_cast<__half*>(&s);
    return __half2float(h);
}
static __device__ __forceinline__ float ldin(const void* p, size_t i, int bfm) {
    return bfm ? b2f(((const short*)p)[i]) : ((const float*)p)[i];
}
static __device__ __forceinline__ float block_reduce(float v, float* red, int t) {
    __syncthreads();
    red[t] = v;
    __syncthreads();
    for (int s = 128; s > 0; s >>= 1) {
        if (t < s) red[t] += red[t + s];
        __syncthreads();
    }
    return red[0];
}

// ---------------------------------------------------------------------------
__global__ void detect_kernel(const unsigned short* __restrict__ lnw_bits, int* __restrict__ flag) {
    if (threadIdx.x == 0 && blockIdx.x == 0)
        *flag = (lnw_bits[0] == 0x3F80u) ? 1 : 0;
}

// ---------------------------------------------------------------------------
// prep: pack transposed bf16 weights + fused biases
// ---------------------------------------------------------------------------
__global__ __launch_bounds__(256) void prep_kernel(
    const void* inv_w1, const void* rbf_w1, const void* inv_w2, const void* rbf_w2,
    const void* inv_b1, const void* rbf_b1, const void* inv_b2, const void* rbf_b2,
    const void* Wq, const void* Wk, const void* Wv,
    const void* Wqs, const void* Wks, const void* Wvs,
    void* ws, const int* __restrict__ flag)
{
    short* W1T = (short*)((char*)ws + OFF_W1T);
    short* W2T = (short*)((char*)ws + OFF_W2T);
    short* WNT = (short*)((char*)ws + OFF_WNT);
    float* b1c = (float*)((char*)ws + OFF_B1);
    float* b2c = (float*)((char*)ws + OFF_B2);
    const int bfm = *flag;
    int g = blockIdx.x * 256 + threadIdx.x;
    if (g < 40960) {                    // W1cat_T [256][160]
        int n = g / 160, k = g % 160;
        float v = 0.f;
        if (n < 120 && k < 112) v = ldin(inv_w1, (size_t)k * 120 + n, bfm);
        else if (n >= 120 && n < 240 && k >= 112 && k < 132)
            v = ldin(rbf_w1, (size_t)(k - 112) * 120 + (n - 120), bfm);
        W1T[g] = f2b(v);
    } else if (g < 73728) {             // W2cat_T [128][256]
        int g2 = g - 40960;
        int n = g2 / 256, k = g2 % 256;
        float v = 0.f;
        if (n < 120) {
            if (k < 120)      v = ldin(inv_w2, (size_t)k * 120 + n, bfm);
            else if (k < 240) v = ldin(rbf_w2, (size_t)(k - 120) * 120 + n, bfm);
        }
        W2T[g2] = f2b(v);
    } else if (g < 172032) {            // WnodeT [768][128]
        int g3 = g - 73728;
        int n = g3 / 128, k = g3 % 128;
        float v = 0.f;
        if (k < 120) {
            if      (n < 120) v = ldin(Wq,  (size_t)k * 120 + n, bfm);
            else if (n < 240) v = ldin(Wk,  (size_t)k * 120 + (n - 120), bfm);
            else if (n < 360) v = ldin(Wv,  (size_t)k * 120 + (n - 240), bfm);
            else if (n < 480) v = ldin(Wqs, (size_t)k * 120 + (n - 360), bfm);
            else if (n < 600) v = ldin(Wks, (size_t)k * 120 + (n - 480), bfm);
            else if (n < 712) v = ldin(Wvs, (size_t)k * 112 + (n - 600), bfm);
        }
        WNT[g3] = f2b(v);
    } else if (g < 172288) {
        int n = g - 172032;
        b1c[n] = (n < 120) ? ldin(inv_b1, n, bfm) : (n < 240 ? ldin(rbf_b1, n - 120, bfm) : 0.f);
    } else if (g < 172416) {
        int n = g - 172288;
        b2c[n] = (n < 120) ? (ldin(inv_b2, n, bfm) + ldin(rbf_b2, n, bfm)) : 0.f;
    }
}

// ---------------------------------------------------------------------------
// nodeln: LN + O3LN -> NS [N,128] bf16, tab equi part (cols 712..951)
// ---------------------------------------------------------------------------
__global__ __launch_bounds__(256) void nodeln_kernel(
    const void* node_scalar, const void* node_equi,
    const void* ln_w, const void* ln_b, const void* o3ln_w,
    void* ws, const int* __restrict__ flag)
{
    __shared__ float red[256];
    short* NS  = (short*)((char*)ws + OFF_NS);
    short* tab = (short*)((char*)ws + OFF_TAB);
    const int n = blockIdx.x, t = threadIdx.x;
    const int bfm = *flag;

    float xs = 0.f;
    if (t < 120) xs = ldin(node_scalar, (size_t)n * 120 + t, bfm);
    float s  = block_reduce(xs, red, t);
    float s2 = block_reduce(xs * xs, red, t);
    float mean = s * (1.f / 120.f);
    float var  = s2 * (1.f / 120.f) - mean * mean;
    float rstd = rsqrtf(var + 1e-5f);
    float nsv = 0.f;
    if (t < 120) nsv = (xs - mean) * rstd * ldin(ln_w, t, bfm) + ldin(ln_b, t, bfm);
    if (t < 128) NS[(size_t)n * 128 + t] = f2b(t < 120 ? nsv : 0.f);

    float xe = 0.f;
    if (t < 240) xe = ldin(node_equi, (size_t)n * 240 + t, bfm);
    float s0  = block_reduce(t < 64 ? xe : 0.f, red, t);
    float mu0 = s0 * (1.f / 64.f);
    float xc  = (t < 64) ? xe - mu0 : xe;
    float ss0 = block_reduce(t < 64 ? xc * xc : 0.f, red, t);
    float ss1 = block_reduce((t >= 64 && t < 160) ? xe * xe : 0.f, red, t);
    float ss2 = block_reduce((t >= 160 && t < 240) ? xe * xe : 0.f, red, t);
    float r0 = rsqrtf(ss0 * (1.f / 64.f) + 1e-5f);
    float r1 = rsqrtf(ss1 * (1.f / 96.f) + 1e-5f);
    float r2 = rsqrtf(ss2 * (1.f / 80.f) + 1e-5f);
    float nev = 0.f;
    if (t < 64)       nev = xc * r0 * ldin(o3ln_w, t, bfm);
    else if (t < 160) nev = xe * r1 * ldin(o3ln_w, 64 + (t - 64) / 3, bfm);
    else if (t < 240) nev = xe * r2 * ldin(o3ln_w, 96 + (t - 160) / 5, bfm);
    if (t < 240) tab[(size_t)n * 952 + 712 + t] = f2b(nev);
}

// ---------------------------------------------------------------------------
// gemm_node: tab[:,0:712] = NS[N,128] @ WnodeT^T  (MFMA bf16, 64x64 tiles)
// ---------------------------------------------------------------------------
__global__ __launch_bounds__(256) void gemm_node_kernel(void* ws)
{
    __shared__ short sA[64 * SB_STRIDE];
    __shared__ short sB[64 * SB_STRIDE];
    const short* NS  = (const short*)((char*)ws + OFF_NS);
    const short* WNT = (const short*)((char*)ws + OFF_WNT);
    short* tab = (short*)((char*)ws + OFF_TAB);

    const int t = threadIdx.x, w = t >> 6, lane = t & 63;
    const int quad = lane >> 4, l15 = lane & 15;
    const int tileM = (blockIdx.x & 255) * 64;
    const int tileN = (blockIdx.x >> 8) * 64;

    f32x4 acc[4];
    for (int i = 0; i < 4; ++i) acc[i] = (f32x4){0.f, 0.f, 0.f, 0.f};

    for (int k0 = 0; k0 < 128; k0 += 32) {
        __syncthreads();
        {
            int row = t >> 2, ch = t & 3;
            *(short8*)&sA[row * SB_STRIDE + ch * 8] =
                *(const short8*)&NS[(size_t)(tileM + row) * 128 + k0 + ch * 8];
            *(short8*)&sB[row * SB_STRIDE + ch * 8] =
                *(const short8*)&WNT[(size_t)(tileN + row) * 128 + k0 + ch * 8];
        }
        __syncthreads();
        short8 a = *(const short8*)&sA[(w * 16 + l15) * SB_STRIDE + quad * 8];
        #pragma unroll
        for (int nt = 0; nt < 4; ++nt) {
            short8 b = *(const short8*)&sB[(nt * 16 + l15) * SB_STRIDE + quad * 8];
            acc[nt] = __builtin_amdgcn_mfma_f32_16x16x32_bf16(a, b, acc[nt], 0, 0, 0);
        }
    }
    #pragma unroll
    for (int nt = 0; nt < 4; ++nt)
        #pragma unroll
        for (int r = 0; r < 4; ++r) {
            int row = tileM + w * 16 + quad * 4 + r;
            int col = tileN + nt * 16 + l15;
            if (col < 712) tab[(size_t)row * 952 + col] = f2b(acc[nt][r]);
        }
}

// ---------------------------------------------------------------------------
// mlp: 64 edges/block.
//   stage A: vectorized gather of equi diffs -> fp16 squares in sD (LDS)
//   stage B: per-irrep reduce + rbf -> F in LDS
//   GEMM1 (F @ W1cat) -> acc[16]; GEMM2 fused via per-wave LDS transpose
//   (H never materialized block-wide; sD/sB/sTr share one LDS region)
// ---------------------------------------------------------------------------
__global__ __launch_bounds__(256, 3) void mlp_kernel(
    const void* rbf, const void* fcut, const int* __restrict__ eidx,
    void* ws, const int* __restrict__ flag)
{
    extern __shared__ __align__(16) char smem[];
    short* sF   = (short*)smem;                          // [64][SF_STRIDE]
    char*  reg1 = smem + 64 * SF_STRIDE * 2;
    short* sD   = (short*)reg1;                          // [64][240] fp16 sq-diffs
    short* sB   = (short*)reg1;                          // [256][SB_STRIDE]
    short* sTr  = (short*)(reg1 + 256 * SB_STRIDE * 2);  // [4][16][TR_STRIDE]
    float* sFc  = (float*)(reg1 + REGION1_BYTES);        // [64]
    int*   sIC  = (int*)(sFc + 64);                      // [64]
    int*   sIN  = sIC + 64;                              // [64]

    const short* tab = (const short*)((char*)ws + OFF_TAB);
    const short* W1T = (const short*)((char*)ws + OFF_W1T);
    const short* W2T = (const short*)((char*)ws + OFF_W2T);
    const float* b1c = (const float*)((char*)ws + OFF_B1);
    const float* b2c = (const float*)((char*)ws + OFF_B2);
    short* Wij = (short*)((char*)ws + OFF_WIJ);

    const int t = threadIdx.x, w = t >> 6, lane = t & 63;
    const int quad = lane >> 4, l15 = lane & 15;
    const int bfm = *flag;
    const int e0 = blockIdx.x * 64;

    // ---- stage edge indices + fcut ----
    if (t < 64)       sIC[t] = eidx[e0 + t];
    else if (t < 128) sIN[t - 64] = eidx[E_EDGES + e0 + (t - 64)];
    else if (t < 192) sFc[t - 128] = ldin(fcut, e0 + (t - 128), bfm);
    __syncthreads();

    // ---- squared diffs: 64 edges x 30 short8 chunks, coalesced 16B loads ----
    for (int u = t; u < 1920; u += 256) {
        int le = u / 30, ch = u - le * 30;
        const short* pc = tab + (size_t)sIC[le] * 952 + 712 + ch * 8;
        const short* pn = tab + (size_t)sIN[le] * 952 + 712 + ch * 8;
        short8 a = *(const short8*)pc;
        short8 b = *(const short8*)pn;
        short8 s;
        #pragma unroll
        for (int j = 0; j < 8; ++j) {
            float d = b2f(b[j]) - b2f(a[j]);
            s[j] = f2h(d * d);
        }
        *(short8*)&sD[le * 240 + ch * 8] = s;
    }
    __syncthreads();

    // ---- per-irrep reduction -> F[:,0:112] ----
    for (int u = t; u < 8192; u += 256) {
        int le = u >> 7, ir = u & 127;
        if (ir < 112) {
            const short* p = sD + le * 240;
            float a;
            if (ir < 64) {
                a = h2f(p[ir]);
            } else if (ir < 96) {
                int off = 64 + 3 * (ir - 64);
                a = h2f(p[off]) + h2f(p[off + 1]) + h2f(p[off + 2]);
            } else {
                int off = 160 + 5 * (ir - 96);
                a = h2f(p[off]) + h2f(p[off + 1]) + h2f(p[off + 2])
                  + h2f(p[off + 3]) + h2f(p[off + 4]);
            }
            sF[le * SF_STRIDE + ir] = f2b(a);
        }
    }
    // ---- rbf + zero pad -> F[:,112:160] ----
    for (int u = t; u < 4096; u += 256) {
        int le = u >> 6, c = u & 63;
        if (c < 48) {
            float v = (c < 20) ? ldin(rbf, (size_t)(e0 + le) * 20 + c, bfm) : 0.f;
            sF[le * SF_STRIDE + 112 + c] = f2b(v);
        }
    }
    __syncthreads();   // sD dead after this point; sB may overwrite region1

    // ---- GEMM1: acc[64,256] = F[64,160] @ W1cat[160,256] ----
    f32x4 acc[16];
    #pragma unroll
    for (int i = 0; i < 16; ++i) acc[i] = (f32x4){0.f, 0.f, 0.f, 0.f};
    for (int k0 = 0; k0 < 160; k0 += 32) {
        #pragma unroll
        for (int i = 0; i < 4; ++i) {
            int u = t + i * 256, n = u >> 2, ch = u & 3;
            *(short8*)&sB[n * SB_STRIDE + ch * 8] =
                *(const short8*)&W1T[(size_t)n * 160 + k0 + ch * 8];
        }
        __syncthreads();
        short8 a = *(const short8*)&sF[(w * 16 + l15) * SF_STRIDE + k0 + quad * 8];
        #pragma unroll
        for (int nt = 0; nt < 16; ++nt) {
            short8 b = *(const short8*)&sB[(nt * 16 + l15) * SB_STRIDE + quad * 8];
            acc[nt] = __builtin_amdgcn_mfma_f32_16x16x32_bf16(a, b, acc[nt], 0, 0, 0);
        }
        __syncthreads();
    }

    // ---- GEMM2 fused: per 32-col slice, silu(acc)+bias -> per-wave LDS
    //      transpose -> A-frag; B slice staged to sB. H rows per wave are
    //      wave-local (GEMM1 rows w*16..w*16+15 == GEMM2 A rows). ----
    short* trw = sTr + w * (16 * TR_STRIDE);
    f32x4 acc2[8];
    #pragma unroll
    for (int i = 0; i < 8; ++i) acc2[i] = (f32x4){0.f, 0.f, 0.f, 0.f};
    #pragma unroll
    for (int ks = 0; ks < 8; ++ks) {
        #pragma unroll
        for (int h = 0; h < 2; ++h) {
            int nt = 2 * ks + h;
            float bb = b1c[nt * 16 + l15];
            #pragma unroll
            for (int r = 0; r < 4; ++r) {
                float v = acc[nt][r] + bb;
                v = v / (1.f + __expf(-v));
                trw[(quad * 4 + r) * TR_STRIDE + h * 16 + l15] = f2b(v);
            }
        }
        #pragma unroll
        for (int i = 0; i < 2; ++i) {
            int u = t + i * 256, n = u >> 2, ch = u & 3;
            *(short8*)&sB[n * SB_STRIDE + ch * 8] =
                *(const short8*)&W2T[(size_t)n * 256 + ks * 32 + ch * 8];
        }
        __syncthreads();
        short8 a = *(const short8*)&trw[l15 * TR_STRIDE + quad * 8];
        #pragma unroll
        for (int nt = 0; nt < 8; ++nt) {
            short8 b = *(const short8*)&sB[(nt * 16 + l15) * SB_STRIDE + quad * 8];
            acc2[nt] = __builtin_amdgcn_mfma_f32_16x16x32_bf16(a, b, acc2[nt], 0, 0, 0);
        }
        __syncthreads();
    }

    #pragma unroll
    for (int nt = 0; nt < 8; ++nt)
        #pragma unroll
        for (int r = 0; r < 4; ++r) {
            int lrow = w * 16 + quad * 4 + r;
            int col = nt * 16 + l15;
            float v = (acc2[nt][r] + b2c[col]) * sFc[lrow];
            Wij[(size_t)(e0 + lrow) * 128 + col] = f2b(v);
        }
}

// ---------------------------------------------------------------------------
// edge2: attention + atomic scatter (one wave per edge)
// ---------------------------------------------------------------------------
__global__ __launch_bounds__(256) void edge2_kernel(
    const void* rsh, const void* fcut, const int* __restrict__ eidx,
    void* ws, const int* __restrict__ flag)
{
    __shared__ float sm[4][248];
    const short* tab = (const short*)((char*)ws + OFF_TAB);
    const short* Wij = (const short*)((char*)ws + OFF_WIJ);
    float* accS = (float*)((char*)ws + OFF_ACC);
    float* accE = accS + (size_t)N_NODES * 120;

    const int t = threadIdx.x, wave = t >> 6, lane = t & 63;
    const int e = blockIdx.x * 4 + wave;
    const int bfm = *flag;
    const int c = eidx[e], n = eidx[E_EDGES + e];
    const short* tc = tab + (size_t)c * 952;
    const short* tn = tab + (size_t)n * 952;
    float* ps   = sm[wave];
    float* pe   = ps + 120;
    float* attn = ps + 240;

    for (int k = lane; k < 120; k += 64) {
        float wv = b2f(Wij[(size_t)e * 128 + k]);
        ps[k] = b2f(tc[k])       * wv * b2f(tn[120 + k]);
        pe[k] = b2f(tc[360 + k]) * wv * b2f(tn[480 + k]);
    }
    __syncthreads();
    if (lane < 4) {
        float a = 0.f;
        #pragma unroll
        for (int d = 0; d < 30; ++d) a += ps[lane * 30 + d];
        attn[lane] = a * SCALE_S;
    } else if (lane < 7) {
        int l = lane - 4;
        float a = 0.f;
        #pragma unroll
        for (int d = 0; d < 40; ++d) a += pe[l * 40 + d];
        attn[4 + l] = a * SCALE_E;
    }
    __syncthreads();

    const float fc = ldin(fcut, e, bfm);
    for (int k = lane; k < 120; k += 64) {
        float m = attn[k / 30] * b2f(tn[240 + k]);
        atomicAdd(&accS[(size_t)c * 120 + k], m);
    }
    for (int j = lane; j < 240; j += 64) {
        int wi, l;
        if (j < 64)       { wi = j;                  l = 0; }
        else if (j < 160) { wi = 64 + (j - 64) / 3;  l = 1; }
        else              { wi = 96 + (j - 160) / 5; l = 2; }
        float m = attn[4 + l] * b2f(tn[600 + wi]) * ldin(rsh, (size_t)e * 240 + j, bfm) * fc;
        atomicAdd(&accE[(size_t)c * 240 + j], m);
    }
}

// ---------------------------------------------------------------------------
// finalize
// ---------------------------------------------------------------------------
__global__ __launch_bounds__(256) void finalize_kernel(
    const void* node_scalar, const void* node_equi,
    void* ws, void* out, const int* __restrict__ flag)
{
    const float* accS = (const float*)((char*)ws + OFF_ACC);
    const float* accE = accS + (size_t)N_NODES * 120;
    const int bfm = *flag;
    int i = blockIdx.x * 256 + threadIdx.x;
    const int NS = N_NODES * 120;
    if (i < NS) {
        float v = ldin(node_scalar, i, bfm) + accS[i];
        if (bfm) ((short*)out)[i] = f2b(v); else ((float*)out)[i] = v;
    } else {
        int j = i - NS;
        float v = ldin(node_equi, j, bfm) + accE[j];
        if (bfm) ((short*)out)[i] = f2b(v); else ((float*)out)[i] = v;
    }
}

extern "C" void kernel_launch(void* const* d_in, const int* in_sizes, int n_in,
                              void* d_out, int out_size, void* d_ws, size_t ws_size,
                              hipStream_t stream) {
    const void* node_scalar = d_in[0];
    const void* node_equi   = d_in[1];
    const void* rbf         = d_in[2];
    const void* fcut        = d_in[3];
    const void* rsh         = d_in[4];
    const void* ln_w        = d_in[5];
    const void* ln_b        = d_in[6];
    const void* o3ln_w      = d_in[7];
    const void* Wq          = d_in[8];
    const void* Wk          = d_in[9];
    const void* Wv          = d_in[10];
    const void* Wqs         = d_in[11];
    const void* Wks         = d_in[12];
    const void* Wvs         = d_in[13];
    const void* rbf_w1      = d_in[14];
    const void* rbf_b1      = d_in[15];
    const void* rbf_w2      = d_in[16];
    const void* rbf_b2      = d_in[17];
    const void* inv_w1      = d_in[18];
    const void* inv_b1      = d_in[19];
    const void* inv_w2      = d_in[20];
    const void* inv_b2      = d_in[21];
    const int*  edge_index  = (const int*)d_in[22];

    int* flag = (int*)d_ws;

    static int smem_set = 0;
    hipFuncSetAttribute(reinterpret_cast<const void*>(mlp_kernel),
                        hipFuncAttributeMaxDynamicSharedMemorySize, SMEM_MLP);
    (void)smem_set;

    detect_kernel<<<1, 64, 0, stream>>>((const unsigned short*)ln_w, flag);
    hipMemsetAsync((char*)d_ws + OFF_ACC, 0, ACC_BYTES, stream);

    prep_kernel<<<674, 256, 0, stream>>>(
        inv_w1, rbf_w1, inv_w2, rbf_w2, inv_b1, rbf_b1, inv_b2, rbf_b2,
        Wq, Wk, Wv, Wqs, Wks, Wvs, d_ws, flag);

    nodeln_kernel<<<N_NODES, 256, 0, stream>>>(
        node_scalar, node_equi, ln_w, ln_b, o3ln_w, d_ws, flag);

    gemm_node_kernel<<<256 * 12, 256, 0, stream>>>(d_ws);

    mlp_kernel<<<E_EDGES / 64, 256, SMEM_MLP, stream>>>(
        rbf, fcut, edge_index, d_ws, flag);

    edge2_kernel<<<E_EDGES / 4, 256, 0, stream>>>(
        rsh, fcut, edge_index, d_ws, flag);

    finalize_kernel<<<(N_NODES * 360) / 256, 256, 0, stream>>>(
        node_scalar, node_equi, d_ws, d_out, flag);
}

// Round 2
// 847.829 us; speedup vs baseline: 1.2944x; 1.0915x over previous
//
#include <hip/hip_runtime.h>
#include <hip/hip_bf16.h>
#include <hip/hip_fp16.h>

#define N_NODES 16384
#define E_EDGES 262144

#define SCALE_S 0.09128709291752768f   // 1/sqrt(120)
#define SCALE_E 0.09449111825230679f   // 1/sqrt(112)

// ---- workspace layout (bytes) ----
#define OFF_ACC   256                       // (reused: CSR sort scratch)
#define ACC_BYTES ((size_t)N_NODES * 360 * 4)
#define OFF_TAB   (OFF_ACC + ACC_BYTES)     // tab N*952 bf16
#define OFF_NS    (OFF_TAB + (size_t)N_NODES * 952 * 2)   // NS N*128 bf16
#define OFF_W1T   (OFF_NS + (size_t)N_NODES * 128 * 2)    // 256*160 bf16
#define OFF_W2T   (OFF_W1T + 256 * 160 * 2)               // 128*256 bf16
#define OFF_WNT   (OFF_W2T + 128 * 256 * 2)               // 768*128 bf16
#define OFF_B1    (OFF_WNT + 768 * 128 * 2)               // 256 f32
#define OFF_B2    (OFF_B1 + 1024)                          // 128 f32
#define OFF_WIJ   (OFF_B2 + 512)                           // E*128 bf16

// CSR sort scratch inside the (otherwise dead) ACC region
#define OFF_CNT   OFF_ACC                   // int[16384]
#define OFF_BASE  (OFF_ACC + 65536)         // int[16385]
#define OFF_CUR   (OFF_ACC + 131584)        // int[16384]
#define OFF_SORT  (OFF_ACC + 197632)        // int[E]
#define SORT_CLR_BYTES 197632

typedef __attribute__((ext_vector_type(8))) short short8;
typedef __attribute__((ext_vector_type(4))) float f32x4;

// padded LDS strides (shorts) to spread banks
#define SF_STRIDE 168   // rows of F  (160 used)
#define SB_STRIDE 40    // rows of B  (32 used)
#define TR_STRIDE 40    // per-wave H transpose buffer rows (32 used)

#define REGION1_BYTES (64 * 240 * 2)
#define SMEM_MLP (64 * SF_STRIDE * 2 + REGION1_BYTES + 64 * 4 + 2 * 64 * 4)

static __device__ __forceinline__ float b2f(short s) {
    return __uint_as_float(((unsigned int)(unsigned short)s) << 16);
}
static __device__ __forceinline__ short f2b(float v) {
    __hip_bfloat16 h = __float2bfloat16(v);
    return *reinterpret_cast<short*>(&h);
}
static __device__ __forceinline__ short f2h(float v) {
    __half h = __float2half(v);
    return *reinterpret_cast<short*>(&h);
}
static __device__ __forceinline__ float h2f(short s) {
    __half h = *reinterpret_cast<__half*>(&s);
    return __half2float(h);
}
static __device__ __forceinline__ float ldin(const void* p, size_t i, int bfm) {
    return bfm ? b2f(((const short*)p)[i]) : ((const float*)p)[i];
}
static __device__ __forceinline__ float block_reduce(float v, float* red, int t) {
    __syncthreads();
    red[t] = v;
    __syncthreads();
    for (int s = 128; s > 0; s >>= 1) {
        if (t < s) red[t] += red[t + s];
        __syncthreads();
    }
    return red[0];
}

// ---------------------------------------------------------------------------
__global__ void detect_kernel(const unsigned short* __restrict__ lnw_bits, int* __restrict__ flag) {
    if (threadIdx.x == 0 && blockIdx.x == 0)
        *flag = (lnw_bits[0] == 0x3F80u) ? 1 : 0;
}

// ---------------------------------------------------------------------------
// CSR build: histogram -> exclusive scan -> scatter edge ids
// ---------------------------------------------------------------------------
__global__ __launch_bounds__(256) void hist_kernel(const int* __restrict__ eidx, void* ws) {
    int* cnt = (int*)((char*)ws + OFF_CNT);
    int e = blockIdx.x * 256 + threadIdx.x;
    atomicAdd(&cnt[eidx[e]], 1);
}

__global__ __launch_bounds__(256) void scan_kernel(void* ws) {
    __shared__ int lds[256];
    int* cnt  = (int*)((char*)ws + OFF_CNT);
    int* base = (int*)((char*)ws + OFF_BASE);
    const int t = threadIdx.x;
    int s = 0;
    for (int j = 0; j < 64; ++j) s += cnt[t * 64 + j];
    lds[t] = s;
    __syncthreads();
    for (int off = 1; off < 256; off <<= 1) {
        int add = (t >= off) ? lds[t - off] : 0;
        __syncthreads();
        lds[t] += add;
        __syncthreads();
    }
    int run = lds[t] - s;          // exclusive prefix of this chunk
    for (int j = 0; j < 64; ++j) {
        int v = cnt[t * 64 + j];
        base[t * 64 + j] = run;
        run += v;
    }
    if (t == 0) base[16384] = E_EDGES;
}

__global__ __launch_bounds__(256) void scatter_kernel(const int* __restrict__ eidx, void* ws) {
    const int* base = (const int*)((char*)ws + OFF_BASE);
    int* cur    = (int*)((char*)ws + OFF_CUR);
    int* sorted = (int*)((char*)ws + OFF_SORT);
    int e = blockIdx.x * 256 + threadIdx.x;
    int c = eidx[e];
    int pos = base[c] + atomicAdd(&cur[c], 1);
    sorted[pos] = e;
}

// ---------------------------------------------------------------------------
// prep: pack transposed bf16 weights + fused biases
// ---------------------------------------------------------------------------
__global__ __launch_bounds__(256) void prep_kernel(
    const void* inv_w1, const void* rbf_w1, const void* inv_w2, const void* rbf_w2,
    const void* inv_b1, const void* rbf_b1, const void* inv_b2, const void* rbf_b2,
    const void* Wq, const void* Wk, const void* Wv,
    const void* Wqs, const void* Wks, const void* Wvs,
    void* ws, const int* __restrict__ flag)
{
    short* W1T = (short*)((char*)ws + OFF_W1T);
    short* W2T = (short*)((char*)ws + OFF_W2T);
    short* WNT = (short*)((char*)ws + OFF_WNT);
    float* b1c = (float*)((char*)ws + OFF_B1);
    float* b2c = (float*)((char*)ws + OFF_B2);
    const int bfm = *flag;
    int g = blockIdx.x * 256 + threadIdx.x;
    if (g < 40960) {                    // W1cat_T [256][160]
        int n = g / 160, k = g % 160;
        float v = 0.f;
        if (n < 120 && k < 112) v = ldin(inv_w1, (size_t)k * 120 + n, bfm);
        else if (n >= 120 && n < 240 && k >= 112 && k < 132)
            v = ldin(rbf_w1, (size_t)(k - 112) * 120 + (n - 120), bfm);
        W1T[g] = f2b(v);
    } else if (g < 73728) {             // W2cat_T [128][256]
        int g2 = g - 40960;
        int n = g2 / 256, k = g2 % 256;
        float v = 0.f;
        if (n < 120) {
            if (k < 120)      v = ldin(inv_w2, (size_t)k * 120 + n, bfm);
            else if (k < 240) v = ldin(rbf_w2, (size_t)(k - 120) * 120 + n, bfm);
        }
        W2T[g2] = f2b(v);
    } else if (g < 172032) {            // WnodeT [768][128]
        int g3 = g - 73728;
        int n = g3 / 128, k = g3 % 128;
        float v = 0.f;
        if (k < 120) {
            if      (n < 120) v = ldin(Wq,  (size_t)k * 120 + n, bfm);
            else if (n < 240) v = ldin(Wk,  (size_t)k * 120 + (n - 120), bfm);
            else if (n < 360) v = ldin(Wv,  (size_t)k * 120 + (n - 240), bfm);
            else if (n < 480) v = ldin(Wqs, (size_t)k * 120 + (n - 360), bfm);
            else if (n < 600) v = ldin(Wks, (size_t)k * 120 + (n - 480), bfm);
            else if (n < 712) v = ldin(Wvs, (size_t)k * 112 + (n - 600), bfm);
        }
        WNT[g3] = f2b(v);
    } else if (g < 172288) {
        int n = g - 172032;
        b1c[n] = (n < 120) ? ldin(inv_b1, n, bfm) : (n < 240 ? ldin(rbf_b1, n - 120, bfm) : 0.f);
    } else if (g < 172416) {
        int n = g - 172288;
        b2c[n] = (n < 120) ? (ldin(inv_b2, n, bfm) + ldin(rbf_b2, n, bfm)) : 0.f;
    }
}

// ---------------------------------------------------------------------------
// nodeln: LN + O3LN -> NS [N,128] bf16, tab equi part (cols 712..951)
// ---------------------------------------------------------------------------
__global__ __launch_bounds__(256) void nodeln_kernel(
    const void* node_scalar, const void* node_equi,
    const void* ln_w, const void* ln_b, const void* o3ln_w,
    void* ws, const int* __restrict__ flag)
{
    __shared__ float red[256];
    short* NS  = (short*)((char*)ws + OFF_NS);
    short* tab = (short*)((char*)ws + OFF_TAB);
    const int n = blockIdx.x, t = threadIdx.x;
    const int bfm = *flag;

    float xs = 0.f;
    if (t < 120) xs = ldin(node_scalar, (size_t)n * 120 + t, bfm);
    float s  = block_reduce(xs, red, t);
    float s2 = block_reduce(xs * xs, red, t);
    float mean = s * (1.f / 120.f);
    float var  = s2 * (1.f / 120.f) - mean * mean;
    float rstd = rsqrtf(var + 1e-5f);
    float nsv = 0.f;
    if (t < 120) nsv = (xs - mean) * rstd * ldin(ln_w, t, bfm) + ldin(ln_b, t, bfm);
    if (t < 128) NS[(size_t)n * 128 + t] = f2b(t < 120 ? nsv : 0.f);

    float xe = 0.f;
    if (t < 240) xe = ldin(node_equi, (size_t)n * 240 + t, bfm);
    float s0  = block_reduce(t < 64 ? xe : 0.f, red, t);
    float mu0 = s0 * (1.f / 64.f);
    float xc  = (t < 64) ? xe - mu0 : xe;
    float ss0 = block_reduce(t < 64 ? xc * xc : 0.f, red, t);
    float ss1 = block_reduce((t >= 64 && t < 160) ? xe * xe : 0.f, red, t);
    float ss2 = block_reduce((t >= 160 && t < 240) ? xe * xe : 0.f, red, t);
    float r0 = rsqrtf(ss0 * (1.f / 64.f) + 1e-5f);
    float r1 = rsqrtf(ss1 * (1.f / 96.f) + 1e-5f);
    float r2 = rsqrtf(ss2 * (1.f / 80.f) + 1e-5f);
    float nev = 0.f;
    if (t < 64)       nev = xc * r0 * ldin(o3ln_w, t, bfm);
    else if (t < 160) nev = xe * r1 * ldin(o3ln_w, 64 + (t - 64) / 3, bfm);
    else if (t < 240) nev = xe * r2 * ldin(o3ln_w, 96 + (t - 160) / 5, bfm);
    if (t < 240) tab[(size_t)n * 952 + 712 + t] = f2b(nev);
}

// ---------------------------------------------------------------------------
// gemm_node: tab[:,0:712] = NS[N,128] @ WnodeT^T  (MFMA bf16, 64x64 tiles)
// ---------------------------------------------------------------------------
__global__ __launch_bounds__(256) void gemm_node_kernel(void* ws)
{
    __shared__ short sA[64 * SB_STRIDE];
    __shared__ short sB[64 * SB_STRIDE];
    const short* NS  = (const short*)((char*)ws + OFF_NS);
    const short* WNT = (const short*)((char*)ws + OFF_WNT);
    short* tab = (short*)((char*)ws + OFF_TAB);

    const int t = threadIdx.x, w = t >> 6, lane = t & 63;
    const int quad = lane >> 4, l15 = lane & 15;
    const int tileM = (blockIdx.x & 255) * 64;
    const int tileN = (blockIdx.x >> 8) * 64;

    f32x4 acc[4];
    for (int i = 0; i < 4; ++i) acc[i] = (f32x4){0.f, 0.f, 0.f, 0.f};

    for (int k0 = 0; k0 < 128; k0 += 32) {
        __syncthreads();
        {
            int row = t >> 2, ch = t & 3;
            *(short8*)&sA[row * SB_STRIDE + ch * 8] =
                *(const short8*)&NS[(size_t)(tileM + row) * 128 + k0 + ch * 8];
            *(short8*)&sB[row * SB_STRIDE + ch * 8] =
                *(const short8*)&WNT[(size_t)(tileN + row) * 128 + k0 + ch * 8];
        }
        __syncthreads();
        short8 a = *(const short8*)&sA[(w * 16 + l15) * SB_STRIDE + quad * 8];
        #pragma unroll
        for (int nt = 0; nt < 4; ++nt) {
            short8 b = *(const short8*)&sB[(nt * 16 + l15) * SB_STRIDE + quad * 8];
            acc[nt] = __builtin_amdgcn_mfma_f32_16x16x32_bf16(a, b, acc[nt], 0, 0, 0);
        }
    }
    #pragma unroll
    for (int nt = 0; nt < 4; ++nt)
        #pragma unroll
        for (int r = 0; r < 4; ++r) {
            int row = tileM + w * 16 + quad * 4 + r;
            int col = tileN + nt * 16 + l15;
            if (col < 712) tab[(size_t)row * 952 + col] = f2b(acc[nt][r]);
        }
}

// ---------------------------------------------------------------------------
// mlp: 64 edges/block (unchanged from last round)
// ---------------------------------------------------------------------------
__global__ __launch_bounds__(256, 3) void mlp_kernel(
    const void* rbf, const void* fcut, const int* __restrict__ eidx,
    void* ws, const int* __restrict__ flag)
{
    extern __shared__ __align__(16) char smem[];
    short* sF   = (short*)smem;                          // [64][SF_STRIDE]
    char*  reg1 = smem + 64 * SF_STRIDE * 2;
    short* sD   = (short*)reg1;                          // [64][240] fp16 sq-diffs
    short* sB   = (short*)reg1;                          // [256][SB_STRIDE]
    short* sTr  = (short*)(reg1 + 256 * SB_STRIDE * 2);  // [4][16][TR_STRIDE]
    float* sFc  = (float*)(reg1 + REGION1_BYTES);        // [64]
    int*   sIC  = (int*)(sFc + 64);                      // [64]
    int*   sIN  = sIC + 64;                              // [64]

    const short* tab = (const short*)((char*)ws + OFF_TAB);
    const short* W1T = (const short*)((char*)ws + OFF_W1T);
    const short* W2T = (const short*)((char*)ws + OFF_W2T);
    const float* b1c = (const float*)((char*)ws + OFF_B1);
    const float* b2c = (const float*)((char*)ws + OFF_B2);
    short* Wij = (short*)((char*)ws + OFF_WIJ);

    const int t = threadIdx.x, w = t >> 6, lane = t & 63;
    const int quad = lane >> 4, l15 = lane & 15;
    const int bfm = *flag;
    const int e0 = blockIdx.x * 64;

    if (t < 64)       sIC[t] = eidx[e0 + t];
    else if (t < 128) sIN[t - 64] = eidx[E_EDGES + e0 + (t - 64)];
    else if (t < 192) sFc[t - 128] = ldin(fcut, e0 + (t - 128), bfm);
    __syncthreads();

    for (int u = t; u < 1920; u += 256) {
        int le = u / 30, ch = u - le * 30;
        const short* pc = tab + (size_t)sIC[le] * 952 + 712 + ch * 8;
        const short* pn = tab + (size_t)sIN[le] * 952 + 712 + ch * 8;
        short8 a = *(const short8*)pc;
        short8 b = *(const short8*)pn;
        short8 s;
        #pragma unroll
        for (int j = 0; j < 8; ++j) {
            float d = b2f(b[j]) - b2f(a[j]);
            s[j] = f2h(d * d);
        }
        *(short8*)&sD[le * 240 + ch * 8] = s;
    }
    __syncthreads();

    for (int u = t; u < 8192; u += 256) {
        int le = u >> 7, ir = u & 127;
        if (ir < 112) {
            const short* p = sD + le * 240;
            float a;
            if (ir < 64) {
                a = h2f(p[ir]);
            } else if (ir < 96) {
                int off = 64 + 3 * (ir - 64);
                a = h2f(p[off]) + h2f(p[off + 1]) + h2f(p[off + 2]);
            } else {
                int off = 160 + 5 * (ir - 96);
                a = h2f(p[off]) + h2f(p[off + 1]) + h2f(p[off + 2])
                  + h2f(p[off + 3]) + h2f(p[off + 4]);
            }
            sF[le * SF_STRIDE + ir] = f2b(a);
        }
    }
    for (int u = t; u < 4096; u += 256) {
        int le = u >> 6, c = u & 63;
        if (c < 48) {
            float v = (c < 20) ? ldin(rbf, (size_t)(e0 + le) * 20 + c, bfm) : 0.f;
            sF[le * SF_STRIDE + 112 + c] = f2b(v);
        }
    }
    __syncthreads();   // sD dead after this point

    f32x4 acc[16];
    #pragma unroll
    for (int i = 0; i < 16; ++i) acc[i] = (f32x4){0.f, 0.f, 0.f, 0.f};
    for (int k0 = 0; k0 < 160; k0 += 32) {
        #pragma unroll
        for (int i = 0; i < 4; ++i) {
            int u = t + i * 256, n = u >> 2, ch = u & 3;
            *(short8*)&sB[n * SB_STRIDE + ch * 8] =
                *(const short8*)&W1T[(size_t)n * 160 + k0 + ch * 8];
        }
        __syncthreads();
        short8 a = *(const short8*)&sF[(w * 16 + l15) * SF_STRIDE + k0 + quad * 8];
        #pragma unroll
        for (int nt = 0; nt < 16; ++nt) {
            short8 b = *(const short8*)&sB[(nt * 16 + l15) * SB_STRIDE + quad * 8];
            acc[nt] = __builtin_amdgcn_mfma_f32_16x16x32_bf16(a, b, acc[nt], 0, 0, 0);
        }
        __syncthreads();
    }

    short* trw = sTr + w * (16 * TR_STRIDE);
    f32x4 acc2[8];
    #pragma unroll
    for (int i = 0; i < 8; ++i) acc2[i] = (f32x4){0.f, 0.f, 0.f, 0.f};
    #pragma unroll
    for (int ks = 0; ks < 8; ++ks) {
        #pragma unroll
        for (int h = 0; h < 2; ++h) {
            int nt = 2 * ks + h;
            float bb = b1c[nt * 16 + l15];
            #pragma unroll
            for (int r = 0; r < 4; ++r) {
                float v = acc[nt][r] + bb;
                v = v / (1.f + __expf(-v));
                trw[(quad * 4 + r) * TR_STRIDE + h * 16 + l15] = f2b(v);
            }
        }
        #pragma unroll
        for (int i = 0; i < 2; ++i) {
            int u = t + i * 256, n = u >> 2, ch = u & 3;
            *(short8*)&sB[n * SB_STRIDE + ch * 8] =
                *(const short8*)&W2T[(size_t)n * 256 + ks * 32 + ch * 8];
        }
        __syncthreads();
        short8 a = *(const short8*)&trw[l15 * TR_STRIDE + quad * 8];
        #pragma unroll
        for (int nt = 0; nt < 8; ++nt) {
            short8 b = *(const short8*)&sB[(nt * 16 + l15) * SB_STRIDE + quad * 8];
            acc2[nt] = __builtin_amdgcn_mfma_f32_16x16x32_bf16(a, b, acc2[nt], 0, 0, 0);
        }
        __syncthreads();
    }

    #pragma unroll
    for (int nt = 0; nt < 8; ++nt)
        #pragma unroll
        for (int r = 0; r < 4; ++r) {
            int lrow = w * 16 + quad * 4 + r;
            int col = nt * 16 + l15;
            float v = (acc2[nt][r] + b2c[col]) * sFc[lrow];
            Wij[(size_t)(e0 + lrow) * 128 + col] = f2b(v);
        }
}

// ---------------------------------------------------------------------------
// edge2g: gather form. One wave per center node; CSR edge list; accumulators
// in VGPRs; shuffle reductions; fused finalize (out = node + acc). No atomics.
// ---------------------------------------------------------------------------
__global__ __launch_bounds__(256) void edge2g_kernel(
    const void* node_scalar, const void* node_equi,
    const void* rsh, const void* fcut, const int* __restrict__ eidx,
    void* ws, void* out, const int* __restrict__ flag)
{
    const short* tab = (const short*)((char*)ws + OFF_TAB);
    const short* Wij = (const short*)((char*)ws + OFF_WIJ);
    const int* base   = (const int*)((char*)ws + OFF_BASE);
    const int* sorted = (const int*)((char*)ws + OFF_SORT);

    const int t = threadIdx.x, wvid = t >> 6, lane = t & 63;
    const int c = blockIdx.x * 4 + wvid;
    const int bfm = *flag;
    const short* tc = tab + (size_t)c * 952;

    // ---- static per-lane index maps ----
    const int i16 = lane & 15, g = lane >> 4;
    // scalar attn reduce: head g (30 elems) over 16 lanes, elems i16 and i16+16
    const int ksa = 30 * g + i16;
    const bool vb = (i16 < 14);
    const int ksb = ksa + 16;
    // equi attn reduce: head g (40 elems, g<3) elems i16, i16+16, i16+32
    const int kea = 40 * g + i16;
    const bool ge = (g < 3), gec = ge && (i16 < 8);
    // cached center q rows
    const float qs_a = b2f(tc[ksa]);
    const float qs_b = vb ? b2f(tc[ksb]) : 0.f;
    const float qe_a = ge  ? b2f(tc[360 + kea])      : 0.f;
    const float qe_b = ge  ? b2f(tc[360 + kea + 16]) : 0.f;
    const float qe_c = gec ? b2f(tc[360 + kea + 32]) : 0.f;
    // accumulation maps
    const int bs0 = 16 * (lane / 30);          // broadcast lane for attn_s[k0/30]
    const int bs1 = 16 * ((lane + 64) / 30);   // for k1 = lane+64
    int wi_[4], be_[4];
    bool jv_[4];
    #pragma unroll
    for (int s = 0; s < 4; ++s) {
        int j = lane + 64 * s;
        jv_[s] = (j < 240);
        int wi = 0, le = 0;
        if (j < 64)       { wi = j;                  le = 0; }
        else if (j < 160) { wi = 64 + (j - 64) / 3;  le = 1; }
        else if (j < 240) { wi = 96 + (j - 160) / 5; le = 2; }
        wi_[s] = wi; be_[s] = 16 * le;
    }

    float accS0 = 0.f, accS1 = 0.f;
    float accE0 = 0.f, accE1 = 0.f, accE2 = 0.f, accE3 = 0.f;

    const int b0 = base[c], b1 = base[c + 1];
    for (int p = b0; p < b1; ++p) {
        const int e = sorted[p];
        const int n = eidx[E_EDGES + e];
        const short* tn = tab + (size_t)n * 952;
        const short* wr = Wij + (size_t)e * 128;
        const float fc = ldin(fcut, e, bfm);

        // partial dot products
        float ps = qs_a * b2f(wr[ksa]) * b2f(tn[120 + ksa])
                 + qs_b * b2f(wr[ksb]) * b2f(tn[120 + ksb]);
        float wv_ea = ge  ? b2f(wr[kea])      : 0.f;
        float wv_eb = ge  ? b2f(wr[kea + 16]) : 0.f;
        float wv_ec = gec ? b2f(wr[kea + 32]) : 0.f;
        float pe = qe_a * wv_ea * b2f(tn[480 + kea])
                 + qe_b * wv_eb * b2f(tn[480 + kea + 16])
                 + qe_c * wv_ec * b2f(tn[480 + kea + 32]);
        // width-16 butterfly: each 16-lane group reduces its own head
        #pragma unroll
        for (int m = 1; m < 16; m <<= 1) {
            ps += __shfl_xor(ps, m, 16);
            pe += __shfl_xor(pe, m, 16);
        }
        ps *= SCALE_S;
        pe *= SCALE_E;

        // scalar message
        float a0 = __shfl(ps, bs0);
        float a1 = __shfl(ps, bs1);
        accS0 += a0 * b2f(tn[240 + lane]);
        if (lane < 56) accS1 += a1 * b2f(tn[240 + 64 + lane]);

        // equi message
        float ae0 = __shfl(pe, be_[0]);
        float ae1 = __shfl(pe, be_[1]);
        float ae2 = __shfl(pe, be_[2]);
        float ae3 = __shfl(pe, be_[3]);
        accE0 += ae0 * b2f(tn[600 + wi_[0]]) * ldin(rsh, (size_t)e * 240 + lane, bfm) * fc;
        accE1 += ae1 * b2f(tn[600 + wi_[1]]) * ldin(rsh, (size_t)e * 240 + lane + 64, bfm) * fc;
        accE2 += ae2 * b2f(tn[600 + wi_[2]]) * ldin(rsh, (size_t)e * 240 + lane + 128, bfm) * fc;
        if (jv_[3])
            accE3 += ae3 * b2f(tn[600 + wi_[3]]) * ldin(rsh, (size_t)e * 240 + lane + 192, bfm) * fc;
    }

    // ---- fused finalize: out = node + acc ----
    const size_t so = (size_t)c * 120;
    {
        float v = ldin(node_scalar, so + lane, bfm) + accS0;
        size_t i = so + lane;
        if (bfm) ((short*)out)[i] = f2b(v); else ((float*)out)[i] = v;
    }
    if (lane < 56) {
        float v = ldin(node_scalar, so + 64 + lane, bfm) + accS1;
        size_t i = so + 64 + lane;
        if (bfm) ((short*)out)[i] = f2b(v); else ((float*)out)[i] = v;
    }
    const size_t eo = (size_t)c * 240;
    const size_t ob = (size_t)N_NODES * 120;
    {
        float v = ldin(node_equi, eo + lane, bfm) + accE0;
        size_t i = ob + eo + lane;
        if (bfm) ((short*)out)[i] = f2b(v); else ((float*)out)[i] = v;
    }
    {
        float v = ldin(node_equi, eo + lane + 64, bfm) + accE1;
        size_t i = ob + eo + lane + 64;
        if (bfm) ((short*)out)[i] = f2b(v); else ((float*)out)[i] = v;
    }
    {
        float v = ldin(node_equi, eo + lane + 128, bfm) + accE2;
        size_t i = ob + eo + lane + 128;
        if (bfm) ((short*)out)[i] = f2b(v); else ((float*)out)[i] = v;
    }
    if (jv_[3]) {
        float v = ldin(node_equi, eo + lane + 192, bfm) + accE3;
        size_t i = ob + eo + lane + 192;
        if (bfm) ((short*)out)[i] = f2b(v); else ((float*)out)[i] = v;
    }
}

extern "C" void kernel_launch(void* const* d_in, const int* in_sizes, int n_in,
                              void* d_out, int out_size, void* d_ws, size_t ws_size,
                              hipStream_t stream) {
    const void* node_scalar = d_in[0];
    const void* node_equi   = d_in[1];
    const void* rbf         = d_in[2];
    const void* fcut        = d_in[3];
    const void* rsh         = d_in[4];
    const void* ln_w        = d_in[5];
    const void* ln_b        = d_in[6];
    const void* o3ln_w      = d_in[7];
    const void* Wq          = d_in[8];
    const void* Wk          = d_in[9];
    const void* Wv          = d_in[10];
    const void* Wqs         = d_in[11];
    const void* Wks         = d_in[12];
    const void* Wvs         = d_in[13];
    const void* rbf_w1      = d_in[14];
    const void* rbf_b1      = d_in[15];
    const void* rbf_w2      = d_in[16];
    const void* rbf_b2      = d_in[17];
    const void* inv_w1      = d_in[18];
    const void* inv_b1      = d_in[19];
    const void* inv_w2      = d_in[20];
    const void* inv_b2      = d_in[21];
    const int*  edge_index  = (const int*)d_in[22];

    int* flag = (int*)d_ws;

    hipFuncSetAttribute(reinterpret_cast<const void*>(mlp_kernel),
                        hipFuncAttributeMaxDynamicSharedMemorySize, SMEM_MLP);

    detect_kernel<<<1, 64, 0, stream>>>((const unsigned short*)ln_w, flag);
    hipMemsetAsync((char*)d_ws + OFF_ACC, 0, SORT_CLR_BYTES, stream);

    // CSR build (independent of node pipeline)
    hist_kernel<<<E_EDGES / 256, 256, 0, stream>>>(edge_index, d_ws);
    scan_kernel<<<1, 256, 0, stream>>>(d_ws);
    scatter_kernel<<<E_EDGES / 256, 256, 0, stream>>>(edge_index, d_ws);

    prep_kernel<<<674, 256, 0, stream>>>(
        inv_w1, rbf_w1, inv_w2, rbf_w2, inv_b1, rbf_b1, inv_b2, rbf_b2,
        Wq, Wk, Wv, Wqs, Wks, Wvs, d_ws, flag);

    nodeln_kernel<<<N_NODES, 256, 0, stream>>>(
        node_scalar, node_equi, ln_w, ln_b, o3ln_w, d_ws, flag);

    gemm_node_kernel<<<256 * 12, 256, 0, stream>>>(d_ws);

    mlp_kernel<<<E_EDGES / 64, 256, SMEM_MLP, stream>>>(
        rbf, fcut, edge_index, d_ws, flag);

    edge2g_kernel<<<N_NODES / 4, 256, 0, stream>>>(
        node_scalar, node_equi, rsh, fcut, edge_index, d_ws, d_out, flag);
}

// Round 3
// 830.120 us; speedup vs baseline: 1.3220x; 1.0213x over previous
//
#include <hip/hip_runtime.h>
#include <hip/hip_bf16.h>
#include <hip/hip_fp16.h>

#define N_NODES 16384
#define E_EDGES 262144

#define SCALE_S 0.09128709291752768f   // 1/sqrt(120)
#define SCALE_E 0.09449111825230679f   // 1/sqrt(112)

// ---- workspace layout (bytes) ----
#define OFF_ACC   256                       // (reused: CSR sort scratch)
#define ACC_BYTES ((size_t)N_NODES * 360 * 4)
#define OFF_TAB   (OFF_ACC + ACC_BYTES)     // tab N*952 bf16
#define OFF_NS    (OFF_TAB + (size_t)N_NODES * 952 * 2)   // NS N*128 bf16
#define OFF_W1T   (OFF_NS + (size_t)N_NODES * 128 * 2)    // 256*160 bf16
#define OFF_W2T   (OFF_W1T + 256 * 160 * 2)               // 128*256 bf16
#define OFF_WNT   (OFF_W2T + 128 * 256 * 2)               // 768*128 bf16
#define OFF_B1    (OFF_WNT + 768 * 128 * 2)               // 256 f32
#define OFF_B2    (OFF_B1 + 1024)                          // 128 f32
#define OFF_WIJ   (OFF_B2 + 512)                           // E*128 bf16

// CSR sort scratch inside the (otherwise dead) ACC region
#define OFF_CNT   OFF_ACC                   // int[16384]
#define OFF_BASE  (OFF_ACC + 65536)         // int[16385]
#define OFF_CUR   (OFF_ACC + 131584)        // int[16384]
#define OFF_SORT  (OFF_ACC + 197632)        // int[E]
#define SORT_CLR_BYTES 197632

typedef __attribute__((ext_vector_type(8))) short short8;
typedef __attribute__((ext_vector_type(4))) float f32x4;

// padded LDS strides (shorts) to spread banks
#define SF_STRIDE 168   // rows of F  (160 used)
#define SB_STRIDE 40    // rows of B  (32 used)
#define TR_STRIDE 40    // per-wave H transpose buffer rows (32 used)

#define REGION1_BYTES (64 * 240 * 2)
#define SMEM_MLP (64 * SF_STRIDE * 2 + REGION1_BYTES + 64 * 4 + 2 * 64 * 4)

static __device__ __forceinline__ float b2f(short s) {
    return __uint_as_float(((unsigned int)(unsigned short)s) << 16);
}
static __device__ __forceinline__ short f2b(float v) {
    __hip_bfloat16 h = __float2bfloat16(v);
    return *reinterpret_cast<short*>(&h);
}
static __device__ __forceinline__ short f2h(float v) {
    __half h = __float2half(v);
    return *reinterpret_cast<short*>(&h);
}
static __device__ __forceinline__ float h2f(short s) {
    __half h = *reinterpret_cast<__half*>(&s);
    return __half2float(h);
}
static __device__ __forceinline__ float ldin(const void* p, size_t i, int bfm) {
    return bfm ? b2f(((const short*)p)[i]) : ((const float*)p)[i];
}

// ---------------------------------------------------------------------------
__global__ void detect_kernel(const unsigned short* __restrict__ lnw_bits, int* __restrict__ flag) {
    if (threadIdx.x == 0 && blockIdx.x == 0)
        *flag = (lnw_bits[0] == 0x3F80u) ? 1 : 0;
}

// ---------------------------------------------------------------------------
// CSR build: histogram -> exclusive scan -> scatter edge ids
// ---------------------------------------------------------------------------
__global__ __launch_bounds__(256) void hist_kernel(const int* __restrict__ eidx, void* ws) {
    int* cnt = (int*)((char*)ws + OFF_CNT);
    int e = blockIdx.x * 256 + threadIdx.x;
    atomicAdd(&cnt[eidx[e]], 1);
}

__global__ __launch_bounds__(256) void scan_kernel(void* ws) {
    __shared__ int lds[256];
    int* cnt  = (int*)((char*)ws + OFF_CNT);
    int* base = (int*)((char*)ws + OFF_BASE);
    const int t = threadIdx.x;
    int s = 0;
    for (int j = 0; j < 64; ++j) s += cnt[t * 64 + j];
    lds[t] = s;
    __syncthreads();
    for (int off = 1; off < 256; off <<= 1) {
        int add = (t >= off) ? lds[t - off] : 0;
        __syncthreads();
        lds[t] += add;
        __syncthreads();
    }
    int run = lds[t] - s;          // exclusive prefix of this chunk
    for (int j = 0; j < 64; ++j) {
        int v = cnt[t * 64 + j];
        base[t * 64 + j] = run;
        run += v;
    }
    if (t == 0) base[16384] = E_EDGES;
}

__global__ __launch_bounds__(256) void scatter_kernel(const int* __restrict__ eidx, void* ws) {
    const int* base = (const int*)((char*)ws + OFF_BASE);
    int* cur    = (int*)((char*)ws + OFF_CUR);
    int* sorted = (int*)((char*)ws + OFF_SORT);
    int e = blockIdx.x * 256 + threadIdx.x;
    int c = eidx[e];
    int pos = base[c] + atomicAdd(&cur[c], 1);
    sorted[pos] = e;
}

// ---------------------------------------------------------------------------
// prep: pack transposed bf16 weights + fused biases
// ---------------------------------------------------------------------------
__global__ __launch_bounds__(256) void prep_kernel(
    const void* inv_w1, const void* rbf_w1, const void* inv_w2, const void* rbf_w2,
    const void* inv_b1, const void* rbf_b1, const void* inv_b2, const void* rbf_b2,
    const void* Wq, const void* Wk, const void* Wv,
    const void* Wqs, const void* Wks, const void* Wvs,
    void* ws, const int* __restrict__ flag)
{
    short* W1T = (short*)((char*)ws + OFF_W1T);
    short* W2T = (short*)((char*)ws + OFF_W2T);
    short* WNT = (short*)((char*)ws + OFF_WNT);
    float* b1c = (float*)((char*)ws + OFF_B1);
    float* b2c = (float*)((char*)ws + OFF_B2);
    const int bfm = *flag;
    int g = blockIdx.x * 256 + threadIdx.x;
    if (g < 40960) {                    // W1cat_T [256][160]
        int n = g / 160, k = g % 160;
        float v = 0.f;
        if (n < 120 && k < 112) v = ldin(inv_w1, (size_t)k * 120 + n, bfm);
        else if (n >= 120 && n < 240 && k >= 112 && k < 132)
            v = ldin(rbf_w1, (size_t)(k - 112) * 120 + (n - 120), bfm);
        W1T[g] = f2b(v);
    } else if (g < 73728) {             // W2cat_T [128][256]
        int g2 = g - 40960;
        int n = g2 / 256, k = g2 % 256;
        float v = 0.f;
        if (n < 120) {
            if (k < 120)      v = ldin(inv_w2, (size_t)k * 120 + n, bfm);
            else if (k < 240) v = ldin(rbf_w2, (size_t)(k - 120) * 120 + n, bfm);
        }
        W2T[g2] = f2b(v);
    } else if (g < 172032) {            // WnodeT [768][128]
        int g3 = g - 73728;
        int n = g3 / 128, k = g3 % 128;
        float v = 0.f;
        if (k < 120) {
            if      (n < 120) v = ldin(Wq,  (size_t)k * 120 + n, bfm);
            else if (n < 240) v = ldin(Wk,  (size_t)k * 120 + (n - 120), bfm);
            else if (n < 360) v = ldin(Wv,  (size_t)k * 120 + (n - 240), bfm);
            else if (n < 480) v = ldin(Wqs, (size_t)k * 120 + (n - 360), bfm);
            else if (n < 600) v = ldin(Wks, (size_t)k * 120 + (n - 480), bfm);
            else if (n < 712) v = ldin(Wvs, (size_t)k * 112 + (n - 600), bfm);
        }
        WNT[g3] = f2b(v);
    } else if (g < 172288) {
        int n = g - 172032;
        b1c[n] = (n < 120) ? ldin(inv_b1, n, bfm) : (n < 240 ? ldin(rbf_b1, n - 120, bfm) : 0.f);
    } else if (g < 172416) {
        int n = g - 172288;
        b2c[n] = (n < 120) ? (ldin(inv_b2, n, bfm) + ldin(rbf_b2, n, bfm)) : 0.f;
    }
}

// ---------------------------------------------------------------------------
// nodeln: LN + O3LN. Shuffle-based reductions: 2 barriers total (was ~80).
// ---------------------------------------------------------------------------
__global__ __launch_bounds__(256) void nodeln_kernel(
    const void* node_scalar, const void* node_equi,
    const void* ln_w, const void* ln_b, const void* o3ln_w,
    void* ws, const int* __restrict__ flag)
{
    __shared__ float sm[24];
    short* NS  = (short*)((char*)ws + OFF_NS);
    short* tab = (short*)((char*)ws + OFF_TAB);
    const int n = blockIdx.x, t = threadIdx.x, wv = t >> 6, lane = t & 63;
    const int bfm = *flag;

    float xs = (t < 120) ? ldin(node_scalar, (size_t)n * 120 + t, bfm) : 0.f;
    float xe = (t < 240) ? ldin(node_equi, (size_t)n * 240 + t, bfm) : 0.f;

    // fused reduce: s, s2, s0(first 64 equi)
    float a = xs, b = xs * xs, c = (t < 64) ? xe : 0.f;
    #pragma unroll
    for (int m = 1; m < 64; m <<= 1) {
        a += __shfl_xor(a, m);
        b += __shfl_xor(b, m);
        c += __shfl_xor(c, m);
    }
    if (lane == 0) { sm[wv * 3] = a; sm[wv * 3 + 1] = b; sm[wv * 3 + 2] = c; }
    __syncthreads();
    float s  = sm[0] + sm[3] + sm[6] + sm[9];
    float s2 = sm[1] + sm[4] + sm[7] + sm[10];
    float s0 = sm[2] + sm[5] + sm[8] + sm[11];

    float mean = s * (1.f / 120.f);
    float var  = s2 * (1.f / 120.f) - mean * mean;
    float rstd = rsqrtf(var + 1e-5f);
    if (t < 128) {
        float nsv = 0.f;
        if (t < 120) nsv = (xs - mean) * rstd * ldin(ln_w, t, bfm) + ldin(ln_b, t, bfm);
        NS[(size_t)n * 128 + t] = f2b(nsv);
    }

    float mu0 = s0 * (1.f / 64.f);
    float xc  = (t < 64) ? xe - mu0 : xe;
    float p0 = (t < 64) ? xc * xc : 0.f;
    float p1 = (t >= 64 && t < 160) ? xe * xe : 0.f;
    float p2 = (t >= 160 && t < 240) ? xe * xe : 0.f;
    #pragma unroll
    for (int m = 1; m < 64; m <<= 1) {
        p0 += __shfl_xor(p0, m);
        p1 += __shfl_xor(p1, m);
        p2 += __shfl_xor(p2, m);
    }
    if (lane == 0) { sm[12 + wv * 3] = p0; sm[12 + wv * 3 + 1] = p1; sm[12 + wv * 3 + 2] = p2; }
    __syncthreads();
    float ss0 = sm[12] + sm[15] + sm[18] + sm[21];
    float ss1 = sm[13] + sm[16] + sm[19] + sm[22];
    float ss2 = sm[14] + sm[17] + sm[20] + sm[23];

    float r0 = rsqrtf(ss0 * (1.f / 64.f) + 1e-5f);
    float r1 = rsqrtf(ss1 * (1.f / 96.f) + 1e-5f);
    float r2 = rsqrtf(ss2 * (1.f / 80.f) + 1e-5f);
    float nev = 0.f;
    if (t < 64)       nev = xc * r0 * ldin(o3ln_w, t, bfm);
    else if (t < 160) nev = xe * r1 * ldin(o3ln_w, 64 + (t - 64) / 3, bfm);
    else if (t < 240) nev = xe * r2 * ldin(o3ln_w, 96 + (t - 160) / 5, bfm);
    if (t < 240) tab[(size_t)n * 952 + 712 + t] = f2b(nev);
}

// ---------------------------------------------------------------------------
// gemm_node: tab[:,0:712] = NS[N,128] @ WnodeT^T  (MFMA bf16, 64x64 tiles)
// ---------------------------------------------------------------------------
__global__ __launch_bounds__(256) void gemm_node_kernel(void* ws)
{
    __shared__ short sA[64 * SB_STRIDE];
    __shared__ short sB[64 * SB_STRIDE];
    const short* NS  = (const short*)((char*)ws + OFF_NS);
    const short* WNT = (const short*)((char*)ws + OFF_WNT);
    short* tab = (short*)((char*)ws + OFF_TAB);

    const int t = threadIdx.x, w = t >> 6, lane = t & 63;
    const int quad = lane >> 4, l15 = lane & 15;
    const int tileM = (blockIdx.x & 255) * 64;
    const int tileN = (blockIdx.x >> 8) * 64;

    f32x4 acc[4];
    for (int i = 0; i < 4; ++i) acc[i] = (f32x4){0.f, 0.f, 0.f, 0.f};

    for (int k0 = 0; k0 < 128; k0 += 32) {
        __syncthreads();
        {
            int row = t >> 2, ch = t & 3;
            *(short8*)&sA[row * SB_STRIDE + ch * 8] =
                *(const short8*)&NS[(size_t)(tileM + row) * 128 + k0 + ch * 8];
            *(short8*)&sB[row * SB_STRIDE + ch * 8] =
                *(const short8*)&WNT[(size_t)(tileN + row) * 128 + k0 + ch * 8];
        }
        __syncthreads();
        short8 a = *(const short8*)&sA[(w * 16 + l15) * SB_STRIDE + quad * 8];
        #pragma unroll
        for (int nt = 0; nt < 4; ++nt) {
            short8 b = *(const short8*)&sB[(nt * 16 + l15) * SB_STRIDE + quad * 8];
            acc[nt] = __builtin_amdgcn_mfma_f32_16x16x32_bf16(a, b, acc[nt], 0, 0, 0);
        }
    }
    #pragma unroll
    for (int nt = 0; nt < 4; ++nt)
        #pragma unroll
        for (int r = 0; r < 4; ++r) {
            int row = tileM + w * 16 + quad * 4 + r;
            int col = tileN + nt * 16 + l15;
            if (col < 712) tab[(size_t)row * 952 + col] = f2b(acc[nt][r]);
        }
}

// ---------------------------------------------------------------------------
// mlp: 64 edges/block (unchanged)
// ---------------------------------------------------------------------------
__global__ __launch_bounds__(256, 3) void mlp_kernel(
    const void* rbf, const void* fcut, const int* __restrict__ eidx,
    void* ws, const int* __restrict__ flag)
{
    extern __shared__ __align__(16) char smem[];
    short* sF   = (short*)smem;                          // [64][SF_STRIDE]
    char*  reg1 = smem + 64 * SF_STRIDE * 2;
    short* sD   = (short*)reg1;                          // [64][240] fp16 sq-diffs
    short* sB   = (short*)reg1;                          // [256][SB_STRIDE]
    short* sTr  = (short*)(reg1 + 256 * SB_STRIDE * 2);  // [4][16][TR_STRIDE]
    float* sFc  = (float*)(reg1 + REGION1_BYTES);        // [64]
    int*   sIC  = (int*)(sFc + 64);                      // [64]
    int*   sIN  = sIC + 64;                              // [64]

    const short* tab = (const short*)((char*)ws + OFF_TAB);
    const short* W1T = (const short*)((char*)ws + OFF_W1T);
    const short* W2T = (const short*)((char*)ws + OFF_W2T);
    const float* b1c = (const float*)((char*)ws + OFF_B1);
    const float* b2c = (const float*)((char*)ws + OFF_B2);
    short* Wij = (short*)((char*)ws + OFF_WIJ);

    const int t = threadIdx.x, w = t >> 6, lane = t & 63;
    const int quad = lane >> 4, l15 = lane & 15;
    const int bfm = *flag;
    const int e0 = blockIdx.x * 64;

    if (t < 64)       sIC[t] = eidx[e0 + t];
    else if (t < 128) sIN[t - 64] = eidx[E_EDGES + e0 + (t - 64)];
    else if (t < 192) sFc[t - 128] = ldin(fcut, e0 + (t - 128), bfm);
    __syncthreads();

    for (int u = t; u < 1920; u += 256) {
        int le = u / 30, ch = u - le * 30;
        const short* pc = tab + (size_t)sIC[le] * 952 + 712 + ch * 8;
        const short* pn = tab + (size_t)sIN[le] * 952 + 712 + ch * 8;
        short8 a = *(const short8*)pc;
        short8 b = *(const short8*)pn;
        short8 s;
        #pragma unroll
        for (int j = 0; j < 8; ++j) {
            float d = b2f(b[j]) - b2f(a[j]);
            s[j] = f2h(d * d);
        }
        *(short8*)&sD[le * 240 + ch * 8] = s;
    }
    __syncthreads();

    for (int u = t; u < 8192; u += 256) {
        int le = u >> 7, ir = u & 127;
        if (ir < 112) {
            const short* p = sD + le * 240;
            float a;
            if (ir < 64) {
                a = h2f(p[ir]);
            } else if (ir < 96) {
                int off = 64 + 3 * (ir - 64);
                a = h2f(p[off]) + h2f(p[off + 1]) + h2f(p[off + 2]);
            } else {
                int off = 160 + 5 * (ir - 96);
                a = h2f(p[off]) + h2f(p[off + 1]) + h2f(p[off + 2])
                  + h2f(p[off + 3]) + h2f(p[off + 4]);
            }
            sF[le * SF_STRIDE + ir] = f2b(a);
        }
    }
    for (int u = t; u < 4096; u += 256) {
        int le = u >> 6, c = u & 63;
        if (c < 48) {
            float v = (c < 20) ? ldin(rbf, (size_t)(e0 + le) * 20 + c, bfm) : 0.f;
            sF[le * SF_STRIDE + 112 + c] = f2b(v);
        }
    }
    __syncthreads();   // sD dead after this point

    f32x4 acc[16];
    #pragma unroll
    for (int i = 0; i < 16; ++i) acc[i] = (f32x4){0.f, 0.f, 0.f, 0.f};
    for (int k0 = 0; k0 < 160; k0 += 32) {
        #pragma unroll
        for (int i = 0; i < 4; ++i) {
            int u = t + i * 256, n = u >> 2, ch = u & 3;
            *(short8*)&sB[n * SB_STRIDE + ch * 8] =
                *(const short8*)&W1T[(size_t)n * 160 + k0 + ch * 8];
        }
        __syncthreads();
        short8 a = *(const short8*)&sF[(w * 16 + l15) * SF_STRIDE + k0 + quad * 8];
        #pragma unroll
        for (int nt = 0; nt < 16; ++nt) {
            short8 b = *(const short8*)&sB[(nt * 16 + l15) * SB_STRIDE + quad * 8];
            acc[nt] = __builtin_amdgcn_mfma_f32_16x16x32_bf16(a, b, acc[nt], 0, 0, 0);
        }
        __syncthreads();
    }

    short* trw = sTr + w * (16 * TR_STRIDE);
    f32x4 acc2[8];
    #pragma unroll
    for (int i = 0; i < 8; ++i) acc2[i] = (f32x4){0.f, 0.f, 0.f, 0.f};
    #pragma unroll
    for (int ks = 0; ks < 8; ++ks) {
        #pragma unroll
        for (int h = 0; h < 2; ++h) {
            int nt = 2 * ks + h;
            float bb = b1c[nt * 16 + l15];
            #pragma unroll
            for (int r = 0; r < 4; ++r) {
                float v = acc[nt][r] + bb;
                v = v / (1.f + __expf(-v));
                trw[(quad * 4 + r) * TR_STRIDE + h * 16 + l15] = f2b(v);
            }
        }
        #pragma unroll
        for (int i = 0; i < 2; ++i) {
            int u = t + i * 256, n = u >> 2, ch = u & 3;
            *(short8*)&sB[n * SB_STRIDE + ch * 8] =
                *(const short8*)&W2T[(size_t)n * 256 + ks * 32 + ch * 8];
        }
        __syncthreads();
        short8 a = *(const short8*)&trw[l15 * TR_STRIDE + quad * 8];
        #pragma unroll
        for (int nt = 0; nt < 8; ++nt) {
            short8 b = *(const short8*)&sB[(nt * 16 + l15) * SB_STRIDE + quad * 8];
            acc2[nt] = __builtin_amdgcn_mfma_f32_16x16x32_bf16(a, b, acc2[nt], 0, 0, 0);
        }
        __syncthreads();
    }

    #pragma unroll
    for (int nt = 0; nt < 8; ++nt)
        #pragma unroll
        for (int r = 0; r < 4; ++r) {
            int lrow = w * 16 + quad * 4 + r;
            int col = nt * 16 + l15;
            float v = (acc2[nt][r] + b2c[col]) * sFc[lrow];
            Wij[(size_t)(e0 + lrow) * 128 + col] = f2b(v);
        }
}

// ---------------------------------------------------------------------------
// edge2g: gather form, 2-deep software pipeline. One wave per center node.
// All operands for edge p+1 prefetched into registers while computing edge p.
// ---------------------------------------------------------------------------
struct ER {
    float wsa, wsb, wea, web, wec;
    float ka, kb, kae, kbe, kce;
    float v0, v1, vs0, vs1, vs2, vs3;
    float r0, r1, r2, r3, fc;
};

__global__ __launch_bounds__(256) void edge2g_kernel(
    const void* node_scalar, const void* node_equi,
    const void* rsh, const void* fcut, const int* __restrict__ eidx,
    void* ws, void* out, const int* __restrict__ flag)
{
    const short* tab = (const short*)((char*)ws + OFF_TAB);
    const short* Wij = (const short*)((char*)ws + OFF_WIJ);
    const int* base   = (const int*)((char*)ws + OFF_BASE);
    const int* sorted = (const int*)((char*)ws + OFF_SORT);

    const int t = threadIdx.x, wvid = t >> 6, lane = t & 63;
    const int c = blockIdx.x * 4 + wvid;
    const int bfm = *flag;
    const short* tc = tab + (size_t)c * 952;

    // ---- static per-lane index maps ----
    const int i16 = lane & 15, g = lane >> 4;
    const int ksa = 30 * g + i16;
    const bool vb = (i16 < 14);
    const int ksb = ksa + 16;                  // <= 121 (cols >=120 of Wij are 0)
    const int kea = 40 * g + i16;
    const bool ge = (g < 3), gec = ge && (i16 < 8);
    const float qs_a = b2f(tc[ksa]);
    const float qs_b = vb ? b2f(tc[ksb]) : 0.f;
    const float qe_a = ge  ? b2f(tc[360 + kea])      : 0.f;
    const float qe_b = ge  ? b2f(tc[360 + kea + 16]) : 0.f;
    const float qe_c = gec ? b2f(tc[360 + kea + 32]) : 0.f;
    const int bs0 = 16 * (lane / 30);
    const int bs1 = 16 * ((lane + 64) / 30);
    const bool jv3 = (lane < 48);
    int wi_[4], be_[4];
    #pragma unroll
    for (int s = 0; s < 4; ++s) {
        int j = lane + 64 * s;
        int wi = 0, le = 0;
        if (j < 64)       { wi = j;                  le = 0; }
        else if (j < 160) { wi = 64 + (j - 64) / 3;  le = 1; }
        else if (j < 240) { wi = 96 + (j - 160) / 5; le = 2; }
        wi_[s] = wi; be_[s] = 16 * le;
    }

    float accS0 = 0.f, accS1 = 0.f;
    float accE0 = 0.f, accE1 = 0.f, accE2 = 0.f, accE3 = 0.f;

    auto loadE = [&](ER& R, int e, int nn) {
        const short* tn = tab + (size_t)nn * 952;
        const short* wr = Wij + (size_t)e * 128;
        R.wsa = b2f(wr[ksa]);
        R.wsb = b2f(wr[ksb]);                       // 0 for cols >=120
        R.ka  = b2f(tn[120 + ksa]);
        R.kb  = b2f(tn[120 + ksb]);                 // junk for vb==false, killed by qs_b=0
        if (ge) {
            R.wea = b2f(wr[kea]);
            R.web = b2f(wr[kea + 16]);
            R.wec = b2f(wr[kea + 32]);              // 0 for cols >=120 (gec false)
        } else { R.wea = 0.f; R.web = 0.f; R.wec = 0.f; }
        R.kae = b2f(tn[480 + kea]);
        R.kbe = b2f(tn[480 + kea + 16]);
        R.kce = b2f(tn[480 + kea + 32]);            // junk killed by qe_c=0
        R.v0  = b2f(tn[240 + lane]);
        R.v1  = b2f(tn[304 + lane]);                // junk for lane>=56, never accumulated
        R.vs0 = b2f(tn[600 + wi_[0]]);
        R.vs1 = b2f(tn[600 + wi_[1]]);
        R.vs2 = b2f(tn[600 + wi_[2]]);
        R.vs3 = b2f(tn[600 + wi_[3]]);
        R.r0  = ldin(rsh, (size_t)e * 240 + lane, bfm);
        R.r1  = ldin(rsh, (size_t)e * 240 + lane + 64, bfm);
        R.r2  = ldin(rsh, (size_t)e * 240 + lane + 128, bfm);
        R.r3  = jv3 ? ldin(rsh, (size_t)e * 240 + lane + 192, bfm) : 0.f;
        R.fc  = ldin(fcut, e, bfm);
    };

    auto computeE = [&](const ER& R) {
        float ps = qs_a * R.wsa * R.ka + qs_b * R.wsb * R.kb;
        float pe = qe_a * R.wea * R.kae + qe_b * R.web * R.kbe + qe_c * R.wec * R.kce;
        #pragma unroll
        for (int m = 1; m < 16; m <<= 1) {
            ps += __shfl_xor(ps, m, 16);
            pe += __shfl_xor(pe, m, 16);
        }
        ps *= SCALE_S;
        pe *= SCALE_E;
        float a0  = __shfl(ps, bs0);
        float a1  = __shfl(ps, bs1);
        float ae0 = __shfl(pe, be_[0]);
        float ae1 = __shfl(pe, be_[1]);
        float ae2 = __shfl(pe, be_[2]);
        float ae3 = __shfl(pe, be_[3]);
        accS0 += a0 * R.v0;
        if (lane < 56) accS1 += a1 * R.v1;
        float fr = R.fc;
        accE0 += ae0 * R.vs0 * R.r0 * fr;
        accE1 += ae1 * R.vs1 * R.r1 * fr;
        accE2 += ae2 * R.vs2 * R.r2 * fr;
        if (jv3) accE3 += ae3 * R.vs3 * R.r3 * fr;
    };

    const int b0v = base[c], b1v = base[c + 1];
    if (b0v < b1v) {
        ER A, B;
        { int e = sorted[b0v]; int nn = eidx[E_EDGES + e]; loadE(A, e, nn); }
        int p = b0v;
        while (true) {
            if (p + 1 < b1v) { int e = sorted[p + 1]; int nn = eidx[E_EDGES + e]; loadE(B, e, nn); }
            computeE(A);
            ++p; if (p >= b1v) break;
            if (p + 1 < b1v) { int e = sorted[p + 1]; int nn = eidx[E_EDGES + e]; loadE(A, e, nn); }
            computeE(B);
            ++p; if (p >= b1v) break;
        }
    }

    // ---- fused finalize: out = node + acc ----
    const size_t so = (size_t)c * 120;
    {
        float v = ldin(node_scalar, so + lane, bfm) + accS0;
        size_t i = so + lane;
        if (bfm) ((short*)out)[i] = f2b(v); else ((float*)out)[i] = v;
    }
    if (lane < 56) {
        float v = ldin(node_scalar, so + 64 + lane, bfm) + accS1;
        size_t i = so + 64 + lane;
        if (bfm) ((short*)out)[i] = f2b(v); else ((float*)out)[i] = v;
    }
    const size_t eo = (size_t)c * 240;
    const size_t ob = (size_t)N_NODES * 120;
    {
        float v = ldin(node_equi, eo + lane, bfm) + accE0;
        size_t i = ob + eo + lane;
        if (bfm) ((short*)out)[i] = f2b(v); else ((float*)out)[i] = v;
    }
    {
        float v = ldin(node_equi, eo + lane + 64, bfm) + accE1;
        size_t i = ob + eo + lane + 64;
        if (bfm) ((short*)out)[i] = f2b(v); else ((float*)out)[i] = v;
    }
    {
        float v = ldin(node_equi, eo + lane + 128, bfm) + accE2;
        size_t i = ob + eo + lane + 128;
        if (bfm) ((short*)out)[i] = f2b(v); else ((float*)out)[i] = v;
    }
    if (jv3) {
        float v = ldin(node_equi, eo + lane + 192, bfm) + accE3;
        size_t i = ob + eo + lane + 192;
        if (bfm) ((short*)out)[i] = f2b(v); else ((float*)out)[i] = v;
    }
}

extern "C" void kernel_launch(void* const* d_in, const int* in_sizes, int n_in,
                              void* d_out, int out_size, void* d_ws, size_t ws_size,
                              hipStream_t stream) {
    const void* node_scalar = d_in[0];
    const void* node_equi   = d_in[1];
    const void* rbf         = d_in[2];
    const void* fcut        = d_in[3];
    const void* rsh         = d_in[4];
    const void* ln_w        = d_in[5];
    const void* ln_b        = d_in[6];
    const void* o3ln_w      = d_in[7];
    const void* Wq          = d_in[8];
    const void* Wk          = d_in[9];
    const void* Wv          = d_in[10];
    const void* Wqs         = d_in[11];
    const void* Wks         = d_in[12];
    const void* Wvs         = d_in[13];
    const void* rbf_w1      = d_in[14];
    const void* rbf_b1      = d_in[15];
    const void* rbf_w2      = d_in[16];
    const void* rbf_b2      = d_in[17];
    const void* inv_w1      = d_in[18];
    const void* inv_b1      = d_in[19];
    const void* inv_w2      = d_in[20];
    const void* inv_b2      = d_in[21];
    const int*  edge_index  = (const int*)d_in[22];

    int* flag = (int*)d_ws;

    hipFuncSetAttribute(reinterpret_cast<const void*>(mlp_kernel),
                        hipFuncAttributeMaxDynamicSharedMemorySize, SMEM_MLP);

    detect_kernel<<<1, 64, 0, stream>>>((const unsigned short*)ln_w, flag);
    hipMemsetAsync((char*)d_ws + OFF_ACC, 0, SORT_CLR_BYTES, stream);

    // CSR build (independent of node pipeline)
    hist_kernel<<<E_EDGES / 256, 256, 0, stream>>>(edge_index, d_ws);
    scan_kernel<<<1, 256, 0, stream>>>(d_ws);
    scatter_kernel<<<E_EDGES / 256, 256, 0, stream>>>(edge_index, d_ws);

    prep_kernel<<<674, 256, 0, stream>>>(
        inv_w1, rbf_w1, inv_w2, rbf_w2, inv_b1, rbf_b1, inv_b2, rbf_b2,
        Wq, Wk, Wv, Wqs, Wks, Wvs, d_ws, flag);

    nodeln_kernel<<<N_NODES, 256, 0, stream>>>(
        node_scalar, node_equi, ln_w, ln_b, o3ln_w, d_ws, flag);

    gemm_node_kernel<<<256 * 12, 256, 0, stream>>>(d_ws);

    mlp_kernel<<<E_EDGES / 64, 256, SMEM_MLP, stream>>>(
        rbf, fcut, edge_index, d_ws, flag);

    edge2g_kernel<<<N_NODES / 4, 256, 0, stream>>>(
        node_scalar, node_equi, rsh, fcut, edge_index, d_ws, d_out, flag);
}

// Round 4
// 730.402 us; speedup vs baseline: 1.5025x; 1.1365x over previous
//
#include <hip/hip_runtime.h>
#include <hip/hip_bf16.h>
#include <hip/hip_fp16.h>

#define N_NODES 16384
#define E_EDGES 262144

#define SCALE_S 0.09128709291752768f   // 1/sqrt(120)
#define SCALE_E 0.09449111825230679f   // 1/sqrt(112)

// ---- workspace layout (bytes) ----
#define OFF_ACC   256                       // (reused: CSR sort scratch)
#define ACC_BYTES ((size_t)N_NODES * 360 * 4)
#define OFF_TAB   (OFF_ACC + ACC_BYTES)     // tab N*952 bf16
#define OFF_NS    (OFF_TAB + (size_t)N_NODES * 952 * 2)   // NS N*128 bf16
#define OFF_W1T   (OFF_NS + (size_t)N_NODES * 128 * 2)    // 256*160 bf16
#define OFF_W2T   (OFF_W1T + 256 * 160 * 2)               // 128*256 bf16
#define OFF_WNT   (OFF_W2T + 128 * 256 * 2)               // 768*128 bf16
#define OFF_B1    (OFF_WNT + 768 * 128 * 2)               // 256 f32
#define OFF_B2    (OFF_B1 + 1024)                          // 128 f32
#define OFF_WIJ   (OFF_B2 + 512)                           // E*128 bf16

// CSR sort scratch inside the (otherwise dead) ACC region
#define OFF_CNT   OFF_ACC                   // int[16384]
#define OFF_BASE  (OFF_ACC + 65536)         // int[16385]
#define OFF_CUR   (OFF_ACC + 131584)        // int[16384]
#define OFF_SORT  (OFF_ACC + 197632)        // int[E]
#define SORT_CLR_BYTES 197632

typedef __attribute__((ext_vector_type(8))) short short8;
typedef __attribute__((ext_vector_type(4))) float f32x4;

// padded LDS strides (shorts) to spread banks
#define SF_STRIDE 168   // rows of F  (160 used)
#define SB_STRIDE 40    // rows of B  (32 used)
#define TR_STRIDE 40    // per-wave H transpose buffer rows (32 used)

#define REGION1_BYTES (64 * 240 * 2)
#define SMEM_MLP (64 * SF_STRIDE * 2 + REGION1_BYTES + 64 * 4 + 2 * 64 * 4)

// edge2g per-wave LDS buffer: wij[128]s @0 (256B) | tn[608]s @256 (1216B) | rsh @1472 (960B)
#define E2_BUF 2432

static __device__ __forceinline__ float b2f(short s) {
    return __uint_as_float(((unsigned int)(unsigned short)s) << 16);
}
static __device__ __forceinline__ short f2b(float v) {
    __hip_bfloat16 h = __float2bfloat16(v);
    return *reinterpret_cast<short*>(&h);
}
static __device__ __forceinline__ short f2h(float v) {
    __half h = __float2half(v);
    return *reinterpret_cast<short*>(&h);
}
static __device__ __forceinline__ float h2f(short s) {
    __half h = *reinterpret_cast<__half*>(&s);
    return __half2float(h);
}
static __device__ __forceinline__ float ldin(const void* p, size_t i, int bfm) {
    return bfm ? b2f(((const short*)p)[i]) : ((const float*)p)[i];
}

// ---------------------------------------------------------------------------
__global__ void detect_kernel(const unsigned short* __restrict__ lnw_bits, int* __restrict__ flag) {
    if (threadIdx.x == 0 && blockIdx.x == 0)
        *flag = (lnw_bits[0] == 0x3F80u) ? 1 : 0;
}

// ---------------------------------------------------------------------------
// CSR build: histogram -> exclusive scan -> scatter edge ids
// ---------------------------------------------------------------------------
__global__ __launch_bounds__(256) void hist_kernel(const int* __restrict__ eidx, void* ws) {
    int* cnt = (int*)((char*)ws + OFF_CNT);
    int e = blockIdx.x * 256 + threadIdx.x;
    atomicAdd(&cnt[eidx[e]], 1);
}

__global__ __launch_bounds__(256) void scan_kernel(void* ws) {
    __shared__ int lds[256];
    int* cnt  = (int*)((char*)ws + OFF_CNT);
    int* base = (int*)((char*)ws + OFF_BASE);
    const int t = threadIdx.x;
    int s = 0;
    for (int j = 0; j < 64; ++j) s += cnt[t * 64 + j];
    lds[t] = s;
    __syncthreads();
    for (int off = 1; off < 256; off <<= 1) {
        int add = (t >= off) ? lds[t - off] : 0;
        __syncthreads();
        lds[t] += add;
        __syncthreads();
    }
    int run = lds[t] - s;          // exclusive prefix of this chunk
    for (int j = 0; j < 64; ++j) {
        int v = cnt[t * 64 + j];
        base[t * 64 + j] = run;
        run += v;
    }
    if (t == 0) base[16384] = E_EDGES;
}

__global__ __launch_bounds__(256) void scatter_kernel(const int* __restrict__ eidx, void* ws) {
    const int* base = (const int*)((char*)ws + OFF_BASE);
    int* cur    = (int*)((char*)ws + OFF_CUR);
    int* sorted = (int*)((char*)ws + OFF_SORT);
    int e = blockIdx.x * 256 + threadIdx.x;
    int c = eidx[e];
    int pos = base[c] + atomicAdd(&cur[c], 1);
    sorted[pos] = e;
}

// ---------------------------------------------------------------------------
// prep: pack transposed bf16 weights + fused biases
// ---------------------------------------------------------------------------
__global__ __launch_bounds__(256) void prep_kernel(
    const void* inv_w1, const void* rbf_w1, const void* inv_w2, const void* rbf_w2,
    const void* inv_b1, const void* rbf_b1, const void* inv_b2, const void* rbf_b2,
    const void* Wq, const void* Wk, const void* Wv,
    const void* Wqs, const void* Wks, const void* Wvs,
    void* ws, const int* __restrict__ flag)
{
    short* W1T = (short*)((char*)ws + OFF_W1T);
    short* W2T = (short*)((char*)ws + OFF_W2T);
    short* WNT = (short*)((char*)ws + OFF_WNT);
    float* b1c = (float*)((char*)ws + OFF_B1);
    float* b2c = (float*)((char*)ws + OFF_B2);
    const int bfm = *flag;
    int g = blockIdx.x * 256 + threadIdx.x;
    if (g < 40960) {                    // W1cat_T [256][160]
        int n = g / 160, k = g % 160;
        float v = 0.f;
        if (n < 120 && k < 112) v = ldin(inv_w1, (size_t)k * 120 + n, bfm);
        else if (n >= 120 && n < 240 && k >= 112 && k < 132)
            v = ldin(rbf_w1, (size_t)(k - 112) * 120 + (n - 120), bfm);
        W1T[g] = f2b(v);
    } else if (g < 73728) {             // W2cat_T [128][256]
        int g2 = g - 40960;
        int n = g2 / 256, k = g2 % 256;
        float v = 0.f;
        if (n < 120) {
            if (k < 120)      v = ldin(inv_w2, (size_t)k * 120 + n, bfm);
            else if (k < 240) v = ldin(rbf_w2, (size_t)(k - 120) * 120 + n, bfm);
        }
        W2T[g2] = f2b(v);
    } else if (g < 172032) {            // WnodeT [768][128]
        int g3 = g - 73728;
        int n = g3 / 128, k = g3 % 128;
        float v = 0.f;
        if (k < 120) {
            if      (n < 120) v = ldin(Wq,  (size_t)k * 120 + n, bfm);
            else if (n < 240) v = ldin(Wk,  (size_t)k * 120 + (n - 120), bfm);
            else if (n < 360) v = ldin(Wv,  (size_t)k * 120 + (n - 240), bfm);
            else if (n < 480) v = ldin(Wqs, (size_t)k * 120 + (n - 360), bfm);
            else if (n < 600) v = ldin(Wks, (size_t)k * 120 + (n - 480), bfm);
            else if (n < 712) v = ldin(Wvs, (size_t)k * 112 + (n - 600), bfm);
        }
        WNT[g3] = f2b(v);
    } else if (g < 172288) {
        int n = g - 172032;
        b1c[n] = (n < 120) ? ldin(inv_b1, n, bfm) : (n < 240 ? ldin(rbf_b1, n - 120, bfm) : 0.f);
    } else if (g < 172416) {
        int n = g - 172288;
        b2c[n] = (n < 120) ? (ldin(inv_b2, n, bfm) + ldin(rbf_b2, n, bfm)) : 0.f;
    }
}

// ---------------------------------------------------------------------------
// nodeln: LN + O3LN. Shuffle-based reductions: 2 barriers total.
// ---------------------------------------------------------------------------
__global__ __launch_bounds__(256) void nodeln_kernel(
    const void* node_scalar, const void* node_equi,
    const void* ln_w, const void* ln_b, const void* o3ln_w,
    void* ws, const int* __restrict__ flag)
{
    __shared__ float sm[24];
    short* NS  = (short*)((char*)ws + OFF_NS);
    short* tab = (short*)((char*)ws + OFF_TAB);
    const int n = blockIdx.x, t = threadIdx.x, wv = t >> 6, lane = t & 63;
    const int bfm = *flag;

    float xs = (t < 120) ? ldin(node_scalar, (size_t)n * 120 + t, bfm) : 0.f;
    float xe = (t < 240) ? ldin(node_equi, (size_t)n * 240 + t, bfm) : 0.f;

    float a = xs, b = xs * xs, c = (t < 64) ? xe : 0.f;
    #pragma unroll
    for (int m = 1; m < 64; m <<= 1) {
        a += __shfl_xor(a, m);
        b += __shfl_xor(b, m);
        c += __shfl_xor(c, m);
    }
    if (lane == 0) { sm[wv * 3] = a; sm[wv * 3 + 1] = b; sm[wv * 3 + 2] = c; }
    __syncthreads();
    float s  = sm[0] + sm[3] + sm[6] + sm[9];
    float s2 = sm[1] + sm[4] + sm[7] + sm[10];
    float s0 = sm[2] + sm[5] + sm[8] + sm[11];

    float mean = s * (1.f / 120.f);
    float var  = s2 * (1.f / 120.f) - mean * mean;
    float rstd = rsqrtf(var + 1e-5f);
    if (t < 128) {
        float nsv = 0.f;
        if (t < 120) nsv = (xs - mean) * rstd * ldin(ln_w, t, bfm) + ldin(ln_b, t, bfm);
        NS[(size_t)n * 128 + t] = f2b(nsv);
    }

    float mu0 = s0 * (1.f / 64.f);
    float xc  = (t < 64) ? xe - mu0 : xe;
    float p0 = (t < 64) ? xc * xc : 0.f;
    float p1 = (t >= 64 && t < 160) ? xe * xe : 0.f;
    float p2 = (t >= 160 && t < 240) ? xe * xe : 0.f;
    #pragma unroll
    for (int m = 1; m < 64; m <<= 1) {
        p0 += __shfl_xor(p0, m);
        p1 += __shfl_xor(p1, m);
        p2 += __shfl_xor(p2, m);
    }
    if (lane == 0) { sm[12 + wv * 3] = p0; sm[12 + wv * 3 + 1] = p1; sm[12 + wv * 3 + 2] = p2; }
    __syncthreads();
    float ss0 = sm[12] + sm[15] + sm[18] + sm[21];
    float ss1 = sm[13] + sm[16] + sm[19] + sm[22];
    float ss2 = sm[14] + sm[17] + sm[20] + sm[23];

    float r0 = rsqrtf(ss0 * (1.f / 64.f) + 1e-5f);
    float r1 = rsqrtf(ss1 * (1.f / 96.f) + 1e-5f);
    float r2 = rsqrtf(ss2 * (1.f / 80.f) + 1e-5f);
    float nev = 0.f;
    if (t < 64)       nev = xc * r0 * ldin(o3ln_w, t, bfm);
    else if (t < 160) nev = xe * r1 * ldin(o3ln_w, 64 + (t - 64) / 3, bfm);
    else if (t < 240) nev = xe * r2 * ldin(o3ln_w, 96 + (t - 160) / 5, bfm);
    if (t < 240) tab[(size_t)n * 952 + 712 + t] = f2b(nev);
}

// ---------------------------------------------------------------------------
// gemm_node: tab[:,0:712] = NS[N,128] @ WnodeT^T  (MFMA bf16, 64x64 tiles)
// ---------------------------------------------------------------------------
__global__ __launch_bounds__(256) void gemm_node_kernel(void* ws)
{
    __shared__ short sA[64 * SB_STRIDE];
    __shared__ short sB[64 * SB_STRIDE];
    const short* NS  = (const short*)((char*)ws + OFF_NS);
    const short* WNT = (const short*)((char*)ws + OFF_WNT);
    short* tab = (short*)((char*)ws + OFF_TAB);

    const int t = threadIdx.x, w = t >> 6, lane = t & 63;
    const int quad = lane >> 4, l15 = lane & 15;
    const int tileM = (blockIdx.x & 255) * 64;
    const int tileN = (blockIdx.x >> 8) * 64;

    f32x4 acc[4];
    for (int i = 0; i < 4; ++i) acc[i] = (f32x4){0.f, 0.f, 0.f, 0.f};

    for (int k0 = 0; k0 < 128; k0 += 32) {
        __syncthreads();
        {
            int row = t >> 2, ch = t & 3;
            *(short8*)&sA[row * SB_STRIDE + ch * 8] =
                *(const short8*)&NS[(size_t)(tileM + row) * 128 + k0 + ch * 8];
            *(short8*)&sB[row * SB_STRIDE + ch * 8] =
                *(const short8*)&WNT[(size_t)(tileN + row) * 128 + k0 + ch * 8];
        }
        __syncthreads();
        short8 a = *(const short8*)&sA[(w * 16 + l15) * SB_STRIDE + quad * 8];
        #pragma unroll
        for (int nt = 0; nt < 4; ++nt) {
            short8 b = *(const short8*)&sB[(nt * 16 + l15) * SB_STRIDE + quad * 8];
            acc[nt] = __builtin_amdgcn_mfma_f32_16x16x32_bf16(a, b, acc[nt], 0, 0, 0);
        }
    }
    #pragma unroll
    for (int nt = 0; nt < 4; ++nt)
        #pragma unroll
        for (int r = 0; r < 4; ++r) {
            int row = tileM + w * 16 + quad * 4 + r;
            int col = tileN + nt * 16 + l15;
            if (col < 712) tab[(size_t)row * 952 + col] = f2b(acc[nt][r]);
        }
}

// ---------------------------------------------------------------------------
// mlp: 64 edges/block (unchanged)
// ---------------------------------------------------------------------------
__global__ __launch_bounds__(256, 3) void mlp_kernel(
    const void* rbf, const void* fcut, const int* __restrict__ eidx,
    void* ws, const int* __restrict__ flag)
{
    extern __shared__ __align__(16) char smem[];
    short* sF   = (short*)smem;                          // [64][SF_STRIDE]
    char*  reg1 = smem + 64 * SF_STRIDE * 2;
    short* sD   = (short*)reg1;                          // [64][240] fp16 sq-diffs
    short* sB   = (short*)reg1;                          // [256][SB_STRIDE]
    short* sTr  = (short*)(reg1 + 256 * SB_STRIDE * 2);  // [4][16][TR_STRIDE]
    float* sFc  = (float*)(reg1 + REGION1_BYTES);        // [64]
    int*   sIC  = (int*)(sFc + 64);                      // [64]
    int*   sIN  = sIC + 64;                              // [64]

    const short* tab = (const short*)((char*)ws + OFF_TAB);
    const short* W1T = (const short*)((char*)ws + OFF_W1T);
    const short* W2T = (const short*)((char*)ws + OFF_W2T);
    const float* b1c = (const float*)((char*)ws + OFF_B1);
    const float* b2c = (const float*)((char*)ws + OFF_B2);
    short* Wij = (short*)((char*)ws + OFF_WIJ);

    const int t = threadIdx.x, w = t >> 6, lane = t & 63;
    const int quad = lane >> 4, l15 = lane & 15;
    const int bfm = *flag;
    const int e0 = blockIdx.x * 64;

    if (t < 64)       sIC[t] = eidx[e0 + t];
    else if (t < 128) sIN[t - 64] = eidx[E_EDGES + e0 + (t - 64)];
    else if (t < 192) sFc[t - 128] = ldin(fcut, e0 + (t - 128), bfm);
    __syncthreads();

    for (int u = t; u < 1920; u += 256) {
        int le = u / 30, ch = u - le * 30;
        const short* pc = tab + (size_t)sIC[le] * 952 + 712 + ch * 8;
        const short* pn = tab + (size_t)sIN[le] * 952 + 712 + ch * 8;
        short8 a = *(const short8*)pc;
        short8 b = *(const short8*)pn;
        short8 s;
        #pragma unroll
        for (int j = 0; j < 8; ++j) {
            float d = b2f(b[j]) - b2f(a[j]);
            s[j] = f2h(d * d);
        }
        *(short8*)&sD[le * 240 + ch * 8] = s;
    }
    __syncthreads();

    for (int u = t; u < 8192; u += 256) {
        int le = u >> 7, ir = u & 127;
        if (ir < 112) {
            const short* p = sD + le * 240;
            float a;
            if (ir < 64) {
                a = h2f(p[ir]);
            } else if (ir < 96) {
                int off = 64 + 3 * (ir - 64);
                a = h2f(p[off]) + h2f(p[off + 1]) + h2f(p[off + 2]);
            } else {
                int off = 160 + 5 * (ir - 96);
                a = h2f(p[off]) + h2f(p[off + 1]) + h2f(p[off + 2])
                  + h2f(p[off + 3]) + h2f(p[off + 4]);
            }
            sF[le * SF_STRIDE + ir] = f2b(a);
        }
    }
    for (int u = t; u < 4096; u += 256) {
        int le = u >> 6, c = u & 63;
        if (c < 48) {
            float v = (c < 20) ? ldin(rbf, (size_t)(e0 + le) * 20 + c, bfm) : 0.f;
            sF[le * SF_STRIDE + 112 + c] = f2b(v);
        }
    }
    __syncthreads();   // sD dead after this point

    f32x4 acc[16];
    #pragma unroll
    for (int i = 0; i < 16; ++i) acc[i] = (f32x4){0.f, 0.f, 0.f, 0.f};
    for (int k0 = 0; k0 < 160; k0 += 32) {
        #pragma unroll
        for (int i = 0; i < 4; ++i) {
            int u = t + i * 256, n = u >> 2, ch = u & 3;
            *(short8*)&sB[n * SB_STRIDE + ch * 8] =
                *(const short8*)&W1T[(size_t)n * 160 + k0 + ch * 8];
        }
        __syncthreads();
        short8 a = *(const short8*)&sF[(w * 16 + l15) * SF_STRIDE + k0 + quad * 8];
        #pragma unroll
        for (int nt = 0; nt < 16; ++nt) {
            short8 b = *(const short8*)&sB[(nt * 16 + l15) * SB_STRIDE + quad * 8];
            acc[nt] = __builtin_amdgcn_mfma_f32_16x16x32_bf16(a, b, acc[nt], 0, 0, 0);
        }
        __syncthreads();
    }

    short* trw = sTr + w * (16 * TR_STRIDE);
    f32x4 acc2[8];
    #pragma unroll
    for (int i = 0; i < 8; ++i) acc2[i] = (f32x4){0.f, 0.f, 0.f, 0.f};
    #pragma unroll
    for (int ks = 0; ks < 8; ++ks) {
        #pragma unroll
        for (int h = 0; h < 2; ++h) {
            int nt = 2 * ks + h;
            float bb = b1c[nt * 16 + l15];
            #pragma unroll
            for (int r = 0; r < 4; ++r) {
                float v = acc[nt][r] + bb;
                v = v / (1.f + __expf(-v));
                trw[(quad * 4 + r) * TR_STRIDE + h * 16 + l15] = f2b(v);
            }
        }
        #pragma unroll
        for (int i = 0; i < 2; ++i) {
            int u = t + i * 256, n = u >> 2, ch = u & 3;
            *(short8*)&sB[n * SB_STRIDE + ch * 8] =
                *(const short8*)&W2T[(size_t)n * 256 + ks * 32 + ch * 8];
        }
        __syncthreads();
        short8 a = *(const short8*)&trw[l15 * TR_STRIDE + quad * 8];
        #pragma unroll
        for (int nt = 0; nt < 8; ++nt) {
            short8 b = *(const short8*)&sB[(nt * 16 + l15) * SB_STRIDE + quad * 8];
            acc2[nt] = __builtin_amdgcn_mfma_f32_16x16x32_bf16(a, b, acc2[nt], 0, 0, 0);
        }
        __syncthreads();
    }

    #pragma unroll
    for (int nt = 0; nt < 8; ++nt)
        #pragma unroll
        for (int r = 0; r < 4; ++r) {
            int lrow = w * 16 + quad * 4 + r;
            int col = nt * 16 + l15;
            float v = (acc2[nt][r] + b2c[col]) * sFc[lrow];
            Wij[(size_t)(e0 + lrow) * 128 + col] = f2b(v);
        }
}

// ---------------------------------------------------------------------------
// edge2g: gather, per-wave LDS double-buffered edge rows.
//   upfront: lane L preloads edge-id/neighbor/fcut for edge L (kills chase)
//   per edge: 4 coalesced vector loads -> regs -> (compute prev) -> ds_write
//   compute reads ~20 scalars from LDS + shuffle reduce. No atomics, no bar.
// ---------------------------------------------------------------------------
struct SG { int wj; short8 ta; int tb; f32x4 rr; };

__global__ __launch_bounds__(256) void edge2g_kernel(
    const void* node_scalar, const void* node_equi,
    const void* rsh, const void* fcut, const int* __restrict__ eidx,
    void* ws, void* out, const int* __restrict__ flag)
{
    __shared__ __align__(16) char sbuf[4][2][E2_BUF];   // 19456 B

    const short* tab = (const short*)((char*)ws + OFF_TAB);
    const short* Wij = (const short*)((char*)ws + OFF_WIJ);
    const int* base   = (const int*)((char*)ws + OFF_BASE);
    const int* sorted = (const int*)((char*)ws + OFF_SORT);

    const int t = threadIdx.x, wvid = t >> 6, lane = t & 63;
    const int c = blockIdx.x * 4 + wvid;
    const int bfm = *flag;
    const short* tc = tab + (size_t)c * 952;

    // ---- static per-lane index maps ----
    const int i16 = lane & 15, g = lane >> 4;
    const int ksa = 30 * g + i16;
    const bool vb = (i16 < 14);
    const int ksb = ksa + 16;                  // <=121; Wij cols>=120 are 0
    const int kea = 40 * g + i16;
    const bool ge = (g < 3), gec = ge && (i16 < 8);
    const float qs_a = b2f(tc[ksa]);
    const float qs_b = vb ? b2f(tc[ksb]) : 0.f;
    const float qe_a = ge  ? b2f(tc[360 + kea])      : 0.f;
    const float qe_b = ge  ? b2f(tc[360 + kea + 16]) : 0.f;
    const float qe_c = gec ? b2f(tc[360 + kea + 32]) : 0.f;
    const int bs0 = 16 * (lane / 30);
    const int bs1 = 16 * ((lane + 64) / 30);
    const bool jv3 = (lane < 48);
    int wi_[4], be_[4];
    #pragma unroll
    for (int s = 0; s < 4; ++s) {
        int j = lane + 64 * s;
        int wi = 0, le = 0;
        if (j < 64)       { wi = j;                  le = 0; }
        else if (j < 160) { wi = 64 + (j - 64) / 3;  le = 1; }
        else if (j < 240) { wi = 96 + (j - 160) / 5; le = 2; }
        wi_[s] = wi; be_[s] = 16 * le;
    }

    float accS0 = 0.f, accS1 = 0.f;
    float accE0 = 0.f, accE1 = 0.f, accE2 = 0.f, accE3 = 0.f;

    const int b0v = base[c], b1v = base[c + 1];
    const int deg = b1v - b0v;

    // upfront parallel preload of edge metadata (first 64 edges)
    int eL = 0, nnL = 0; float fcL = 0.f;
    if (lane < deg) {
        int ee = sorted[b0v + lane];
        eL = ee;
        nnL = eidx[E_EDGES + ee];
        fcL = ldin(fcut, ee, bfm);
    }

    auto getE = [&](int p, int& e, int& nn, float& fc) {
        if (p < 64) { e = __shfl(eL, p); nn = __shfl(nnL, p); fc = __shfl(fcL, p); }
        else {
            e = sorted[b0v + p];
            nn = eidx[E_EDGES + e];
            fc = ldin(fcut, e, bfm);
        }
    };

    auto gload = [&](int e, int nn) -> SG {
        SG L;
        const int* wr32 = (const int*)(Wij + (size_t)e * 128);
        L.wj = wr32[lane];                                          // 256 B
        const short* tnp = tab + (size_t)nn * 952 + 120;
        L.ta = ((const short8*)tnp)[lane];                          // 1024 B
        L.tb = (lane < 48) ? *(const int*)(tnp + 512 + lane * 2) : 0; // 192 B
        if (bfm) {
            const short* rp = (const short*)rsh + (size_t)e * 240;
            L.rr = (lane < 30) ? *(const f32x4*)(rp + lane * 8) : (f32x4){0.f,0.f,0.f,0.f};
        } else {
            const float* rp = (const float*)rsh + (size_t)e * 240;
            L.rr = (lane < 60) ? *(const f32x4*)(rp + lane * 4) : (f32x4){0.f,0.f,0.f,0.f};
        }
        return L;
    };

    auto dswrite = [&](char* buf, const SG& L) {
        ((int*)buf)[lane] = L.wj;
        *(short8*)(buf + 256 + lane * 16) = L.ta;
        if (lane < 48) *(int*)(buf + 1280 + lane * 4) = L.tb;
        if (lane < (bfm ? 30 : 60)) *(f32x4*)(buf + 1472 + lane * 16) = L.rr;
    };

    auto computeB = [&](const char* buf, float fc) {
        const short* W = (const short*)buf;
        const short* T = (const short*)(buf + 256);
        float ps = qs_a * b2f(W[ksa]) * b2f(T[ksa])
                 + qs_b * b2f(W[ksb]) * b2f(T[ksb]);
        float pe = 0.f;
        if (ge) {
            pe = qe_a * b2f(W[kea])      * b2f(T[360 + kea])
               + qe_b * b2f(W[kea + 16]) * b2f(T[360 + kea + 16])
               + qe_c * b2f(W[kea + 32]) * b2f(T[360 + kea + 32]);
        }
        #pragma unroll
        for (int m = 1; m < 16; m <<= 1) {
            ps += __shfl_xor(ps, m, 16);
            pe += __shfl_xor(pe, m, 16);
        }
        ps *= SCALE_S;
        pe *= SCALE_E;
        float a0  = __shfl(ps, bs0);
        float a1  = __shfl(ps, bs1);
        float ae0 = __shfl(pe, be_[0]);
        float ae1 = __shfl(pe, be_[1]);
        float ae2 = __shfl(pe, be_[2]);
        float ae3 = __shfl(pe, be_[3]);
        accS0 += a0 * b2f(T[120 + lane]);
        if (lane < 56) accS1 += a1 * b2f(T[184 + lane]);
        float r0, r1, r2, r3;
        if (bfm) {
            const short* R = (const short*)(buf + 1472);
            r0 = b2f(R[lane]); r1 = b2f(R[lane + 64]); r2 = b2f(R[lane + 128]);
            r3 = jv3 ? b2f(R[lane + 192]) : 0.f;
        } else {
            const float* R = (const float*)(buf + 1472);
            r0 = R[lane]; r1 = R[lane + 64]; r2 = R[lane + 128];
            r3 = jv3 ? R[lane + 192] : 0.f;
        }
        accE0 += ae0 * b2f(T[480 + wi_[0]]) * r0 * fc;
        accE1 += ae1 * b2f(T[480 + wi_[1]]) * r1 * fc;
        accE2 += ae2 * b2f(T[480 + wi_[2]]) * r2 * fc;
        if (jv3) accE3 += ae3 * b2f(T[480 + wi_[3]]) * r3 * fc;
    };

    if (deg > 0) {
        char* buf0 = sbuf[wvid][0];
        char* buf1 = sbuf[wvid][1];
        int e, nn; float fcC, fcN;
        getE(0, e, nn, fcC);
        SG L = gload(e, nn);
        dswrite(buf0, L);
        for (int p = 0; p < deg; ++p) {
            char* cur = (p & 1) ? buf1 : buf0;
            char* nxt = (p & 1) ? buf0 : buf1;
            bool more = (p + 1 < deg);
            if (more) { getE(p + 1, e, nn, fcN); L = gload(e, nn); }
            computeB(cur, fcC);
            if (more) { dswrite(nxt, L); fcC = fcN; }
        }
    }

    // ---- fused finalize: out = node + acc ----
    const size_t so = (size_t)c * 120;
    {
        float v = ldin(node_scalar, so + lane, bfm) + accS0;
        size_t i = so + lane;
        if (bfm) ((short*)out)[i] = f2b(v); else ((float*)out)[i] = v;
    }
    if (lane < 56) {
        float v = ldin(node_scalar, so + 64 + lane, bfm) + accS1;
        size_t i = so + 64 + lane;
        if (bfm) ((short*)out)[i] = f2b(v); else ((float*)out)[i] = v;
    }
    const size_t eo = (size_t)c * 240;
    const size_t ob = (size_t)N_NODES * 120;
    {
        float v = ldin(node_equi, eo + lane, bfm) + accE0;
        size_t i = ob + eo + lane;
        if (bfm) ((short*)out)[i] = f2b(v); else ((float*)out)[i] = v;
    }
    {
        float v = ldin(node_equi, eo + lane + 64, bfm) + accE1;
        size_t i = ob + eo + lane + 64;
        if (bfm) ((short*)out)[i] = f2b(v); else ((float*)out)[i] = v;
    }
    {
        float v = ldin(node_equi, eo + lane + 128, bfm) + accE2;
        size_t i = ob + eo + lane + 128;
        if (bfm) ((short*)out)[i] = f2b(v); else ((float*)out)[i] = v;
    }
    if (jv3) {
        float v = ldin(node_equi, eo + lane + 192, bfm) + accE3;
        size_t i = ob + eo + lane + 192;
        if (bfm) ((short*)out)[i] = f2b(v); else ((float*)out)[i] = v;
    }
}

extern "C" void kernel_launch(void* const* d_in, const int* in_sizes, int n_in,
                              void* d_out, int out_size, void* d_ws, size_t ws_size,
                              hipStream_t stream) {
    const void* node_scalar = d_in[0];
    const void* node_equi   = d_in[1];
    const void* rbf         = d_in[2];
    const void* fcut        = d_in[3];
    const void* rsh         = d_in[4];
    const void* ln_w        = d_in[5];
    const void* ln_b        = d_in[6];
    const void* o3ln_w      = d_in[7];
    const void* Wq          = d_in[8];
    const void* Wk          = d_in[9];
    const void* Wv          = d_in[10];
    const void* Wqs         = d_in[11];
    const void* Wks         = d_in[12];
    const void* Wvs         = d_in[13];
    const void* rbf_w1      = d_in[14];
    const void* rbf_b1      = d_in[15];
    const void* rbf_w2      = d_in[16];
    const void* rbf_b2      = d_in[17];
    const void* inv_w1      = d_in[18];
    const void* inv_b1      = d_in[19];
    const void* inv_w2      = d_in[20];
    const void* inv_b2      = d_in[21];
    const int*  edge_index  = (const int*)d_in[22];

    int* flag = (int*)d_ws;

    hipFuncSetAttribute(reinterpret_cast<const void*>(mlp_kernel),
                        hipFuncAttributeMaxDynamicSharedMemorySize, SMEM_MLP);

    detect_kernel<<<1, 64, 0, stream>>>((const unsigned short*)ln_w, flag);
    hipMemsetAsync((char*)d_ws + OFF_ACC, 0, SORT_CLR_BYTES, stream);

    // CSR build (independent of node pipeline)
    hist_kernel<<<E_EDGES / 256, 256, 0, stream>>>(edge_index, d_ws);
    scan_kernel<<<1, 256, 0, stream>>>(d_ws);
    scatter_kernel<<<E_EDGES / 256, 256, 0, stream>>>(edge_index, d_ws);

    prep_kernel<<<674, 256, 0, stream>>>(
        inv_w1, rbf_w1, inv_w2, rbf_w2, inv_b1, rbf_b1, inv_b2, rbf_b2,
        Wq, Wk, Wv, Wqs, Wks, Wvs, d_ws, flag);

    nodeln_kernel<<<N_NODES, 256, 0, stream>>>(
        node_scalar, node_equi, ln_w, ln_b, o3ln_w, d_ws, flag);

    gemm_node_kernel<<<256 * 12, 256, 0, stream>>>(d_ws);

    mlp_kernel<<<E_EDGES / 64, 256, SMEM_MLP, stream>>>(
        rbf, fcut, edge_index, d_ws, flag);

    edge2g_kernel<<<N_NODES / 4, 256, 0, stream>>>(
        node_scalar, node_equi, rsh, fcut, edge_index, d_ws, d_out, flag);
}